// Round 4
// baseline (71586.591 us; speedup 1.0000x reference)
//
#include <hip/hip_runtime.h>
#include <hip/hip_bf16.h>

// Seq2Seq GRU+attention, MI355X. Round 4: identical to round-3 submission
// (infra failure last round, no signal). bf16/MFMA build + decoder n-gate fix.

#define B_  32
#define TX_ 512
#define TY_ 127
#define E_  256
#define H_  512
#define G3_ 1536
#define V_  32000

typedef unsigned short u16;
typedef short short8 __attribute__((ext_vector_type(8)));
typedef float f32x4 __attribute__((ext_vector_type(4)));

__device__ __forceinline__ float bfu(u16 h){ union{unsigned u; float f;} x; x.u=((unsigned)h)<<16; return x.f; }
__device__ __forceinline__ float bflo(unsigned p){ union{unsigned u; float f;} x; x.u=p<<16; return x.f; }
__device__ __forceinline__ float bfhi(unsigned p){ union{unsigned u; float f;} x; x.u=p&0xffff0000u; return x.f; }
__device__ __forceinline__ u16 f2bf(float f){ union{float f; unsigned u;} v; v.f=f; unsigned r=v.u+0x7fffu+((v.u>>16)&1u); return (u16)(r>>16); }
__device__ __forceinline__ float sigm(float x){ return 1.f/(1.f+__expf(-x)); }
__device__ __forceinline__ float tanh_f(float x){ return 1.f - 2.f/(__expf(2.f*x)+1.f); }
__device__ __forceinline__ float4 ld4(const float* p){ return *(const float4*)p; }
__device__ __forceinline__ float dot4(float4 a, float4 b, float acc){
  acc=fmaf(a.x,b.x,acc); acc=fmaf(a.y,b.y,acc); acc=fmaf(a.z,b.z,acc); acc=fmaf(a.w,b.w,acc); return acc;
}

// ---------- f32 -> bf16 row converter (handles strided source rows) ----------
__global__ void cvt_rows(const float* __restrict__ src, int sld, int soff,
                         u16* __restrict__ dst, int cols){
  int r = blockIdx.x;
  const float* s = src + (size_t)r*sld + soff;
  u16* d = dst + (size_t)r*cols;
  for (int c = threadIdx.x; c < cols; c += blockDim.x) d[c] = f2bf(s[c]);
}

// ---------- embedding gather -> bf16 rows (E_=256 threads per row) ----------
__global__ void gather_embed(const float* __restrict__ emb, const int* __restrict__ idx,
                             u16* __restrict__ dst, int rows_per_b, int ld){
  int m = blockIdx.x;
  int bb = m / rows_per_b, tt = m - bb*rows_per_b;
  int id = idx[bb*ld + tt];
  dst[(size_t)m*E_ + threadIdx.x] = f2bf(emb[(size_t)id*E_ + threadIdx.x]);
}

// ---------- bf16 MFMA GEMM: C[M,N] = A[M,K] @ B[N,K]^T + bias ----------
// 256 thr = 4 waves, 128x128/WG, 64x64/wave (4x4 16x16x32 fragments).
// D mapping (m89-verified): row=(l>>4)*4+r, col=l&15.
__global__ __launch_bounds__(256) void gemm_bf16(
    const u16* __restrict__ A, int lda, const u16* __restrict__ Bm, int ldb,
    void* __restrict__ Cout, int ldc, const float* __restrict__ bias,
    int M, int K, int out_bf16)
{
  int wave = threadIdx.x >> 6, lane = threadIdx.x & 63;
  int m0 = blockIdx.x*128 + (wave>>1)*64;
  int n0 = blockIdx.y*128 + (wave&1)*64;
  int lr = lane & 15, lk = (lane>>4)*8;
  f32x4 acc[4][4];
  #pragma unroll
  for (int i=0;i<4;++i)
    #pragma unroll
    for (int j=0;j<4;++j) acc[i][j] = (f32x4){0.f,0.f,0.f,0.f};

  for (int k0=0; k0<K; k0+=32){
    short8 af[4], bfv[4];
    #pragma unroll
    for (int i=0;i<4;++i){
      int row = m0 + i*16 + lr; if (row > M-1) row = M-1;   // clamp (store-guarded)
      af[i] = *(const short8*)(A + (size_t)row*lda + k0 + lk);
    }
    #pragma unroll
    for (int j=0;j<4;++j){
      int col = n0 + j*16 + lr;
      bfv[j] = *(const short8*)(Bm + (size_t)col*ldb + k0 + lk);
    }
    #pragma unroll
    for (int i=0;i<4;++i)
      #pragma unroll
      for (int j=0;j<4;++j)
        acc[i][j] = __builtin_amdgcn_mfma_f32_16x16x32_bf16(af[i], bfv[j], acc[i][j], 0,0,0);
  }
  int rbase = (lane>>4)*4;
  #pragma unroll
  for (int i=0;i<4;++i){
    #pragma unroll
    for (int r=0;r<4;++r){
      int row = m0 + i*16 + rbase + r;
      if (row < M){
        #pragma unroll
        for (int j=0;j<4;++j){
          int col = n0 + j*16 + lr;
          float v = acc[i][j][r] + bias[col];
          if (out_bf16) ((u16*)Cout)[(size_t)row*ldc + col] = f2bf(v);
          else          ((float*)Cout)[(size_t)row*ldc + col] = v;
        }
      }
    }
  }
}

// ---------- encoder: 32 WGs (1 per batch) x 512 thr; thread u owns unit u ----------
__global__ __launch_bounds__(512) void enc_kernel(
    const u16* __restrict__ Gx, const float* __restrict__ Whh,
    const float* __restrict__ bhh, u16* __restrict__ eh)
{
  int b = blockIdx.x, u = threadIdx.x;
  __shared__ __align__(16) float hs[H_];
  hs[u] = 0.f;
  const float* wr = Whh + (size_t)u*H_;
  const float* wz = Whh + (size_t)(u+H_)*H_;
  const float* wn = Whh + (size_t)(u+2*H_)*H_;
  float br = bhh[u], bz = bhh[u+H_], bn = bhh[u+2*H_];
  __syncthreads();
  for (int t=0;t<TX_;++t){
    float gr=br, gz=bz, gn=bn;
    #pragma unroll 2
    for (int k=0;k<H_;k+=16){
      float4 h0=ld4(&hs[k]), h1=ld4(&hs[k+4]), h2=ld4(&hs[k+8]), h3=ld4(&hs[k+12]);
      gr=dot4(h0,ld4(wr+k),gr); gr=dot4(h1,ld4(wr+k+4),gr); gr=dot4(h2,ld4(wr+k+8),gr); gr=dot4(h3,ld4(wr+k+12),gr);
      gz=dot4(h0,ld4(wz+k),gz); gz=dot4(h1,ld4(wz+k+4),gz); gz=dot4(h2,ld4(wz+k+8),gz); gz=dot4(h3,ld4(wz+k+12),gz);
      gn=dot4(h0,ld4(wn+k),gn); gn=dot4(h1,ld4(wn+k+4),gn); gn=dot4(h2,ld4(wn+k+8),gn); gn=dot4(h3,ld4(wn+k+12),gn);
    }
    size_t base = (size_t)(b*TX_ + t)*G3_;
    float ir=bfu(Gx[base+u]), iz=bfu(Gx[base+H_+u]), inn=bfu(Gx[base+2*H_+u]);
    float r = sigm(ir+gr), z = sigm(iz+gz);
    float n = tanh_f(inn + r*gn);           // encoder: whole input part is in inn -> correct
    float hnew = (1.f-z)*n + z*hs[u];
    __syncthreads();
    hs[u] = hnew;
    eh[(size_t)(b*TX_ + t)*H_ + u] = f2bf(hnew);
    __syncthreads();
  }
}

// ---------- eh[b][t][u] -> ehT[b][u][t] (64x64 LDS tiles) ----------
__global__ __launch_bounds__(256) void transpose_eh(const u16* __restrict__ eh, u16* __restrict__ ehT){
  int b = blockIdx.x, tb = blockIdx.y, ub = blockIdx.z;
  __shared__ u16 tile[64][65];
  int c = threadIdx.x & 63, r0 = threadIdx.x >> 6;
  const u16* src = eh + (size_t)b*TX_*H_;
  #pragma unroll
  for (int r=r0; r<64; r+=4) tile[r][c] = src[(size_t)(tb*64+r)*H_ + ub*64 + c];
  __syncthreads();
  u16* dst = ehT + (size_t)b*H_*TX_;
  #pragma unroll
  for (int r=r0; r<64; r+=4) dst[(size_t)(ub*64+r)*TX_ + tb*64 + c] = tile[c][r];
}

// ---------- decoder: 32 WGs x 512 thr; thread u = attention key index AND unit ----------
__global__ __launch_bounds__(512) void dec_kernel(
    const u16* __restrict__ eh, const u16* __restrict__ ehT,
    const u16* __restrict__ Gy,
    const float* __restrict__ Wih, const float* __restrict__ Whh,
    const float* __restrict__ bhh, const float* __restrict__ hinit,
    u16* __restrict__ Xfc)
{
  int b = blockIdx.x, u = threadIdx.x;
  __shared__ __align__(16) float oxs[H_], hxs[H_], sxs[H_], sc[TX_], red[TX_];
  oxs[u] = hinit[u];
  hxs[u] = 0.f;
  const u16* ehb  = eh  + (size_t)b*TX_*H_;
  const u16* ehTb = ehT + (size_t)b*H_*TX_;
  const float* wsr = Wih + (size_t)u*(E_+H_) + E_;
  const float* wsz = Wih + (size_t)(u+H_)*(E_+H_) + E_;
  const float* wsn = Wih + (size_t)(u+2*H_)*(E_+H_) + E_;
  const float* whr = Whh + (size_t)u*H_;
  const float* whz = Whh + (size_t)(u+H_)*H_;
  const float* whn = Whh + (size_t)(u+2*H_)*H_;
  float br=bhh[u], bz=bhh[u+H_], bn=bhh[u+2*H_];
  __syncthreads();
  for (int t=0;t<TY_;++t){
    // 1) scores[t'=u] = dot(eh[b][u][:], ox)
    float s = 0.f;
    const u16* er = ehb + (size_t)u*H_;
    #pragma unroll 2
    for (int k=0;k<H_;k+=8){
      uint4 ev = *(const uint4*)(er + k);
      float4 o1 = ld4(&oxs[k]), o2 = ld4(&oxs[k+4]);
      s = fmaf(bflo(ev.x),o1.x,s); s = fmaf(bfhi(ev.x),o1.y,s);
      s = fmaf(bflo(ev.y),o1.z,s); s = fmaf(bfhi(ev.y),o1.w,s);
      s = fmaf(bflo(ev.z),o2.x,s); s = fmaf(bfhi(ev.z),o2.y,s);
      s = fmaf(bflo(ev.w),o2.z,s); s = fmaf(bfhi(ev.w),o2.w,s);
    }
    red[u] = s; __syncthreads();
    #pragma unroll
    for (int off=256; off>0; off>>=1){ if (u<off) red[u]=fmaxf(red[u],red[u+off]); __syncthreads(); }
    float m = red[0]; __syncthreads();
    float pexp = __expf(s - m);
    red[u] = pexp; __syncthreads();
    #pragma unroll
    for (int off=256; off>0; off>>=1){ if (u<off) red[u]+=red[u+off]; __syncthreads(); }
    float inv = 1.f/red[0];
    sc[u] = pexp*inv; __syncthreads();
    // 2) sx[u] = sum_t ehT[b][u][t]*a[t]
    float sx = 0.f;
    const u16* etr = ehTb + (size_t)u*TX_;
    #pragma unroll 2
    for (int k=0;k<TX_;k+=8){
      uint4 ev = *(const uint4*)(etr + k);
      float4 a1 = ld4(&sc[k]), a2 = ld4(&sc[k+4]);
      sx = fmaf(bflo(ev.x),a1.x,sx); sx = fmaf(bfhi(ev.x),a1.y,sx);
      sx = fmaf(bflo(ev.y),a1.z,sx); sx = fmaf(bfhi(ev.y),a1.w,sx);
      sx = fmaf(bflo(ev.z),a2.x,sx); sx = fmaf(bfhi(ev.z),a2.y,sx);
      sx = fmaf(bflo(ev.w),a2.z,sx); sx = fmaf(bfhi(ev.w),a2.w,sx);
    }
    sxs[u] = sx; __syncthreads();
    // 3) GRU gates for unit u.
    //    FIX: sx-part of W_ih (gni) is part of i_n -> NOT scaled by r.
    //         Only the W_hh part (gnh, incl. bhh_n) is scaled by r.
    float gr=br, gz=bz, gni=0.f, gnh=bn;
    for (int k=0;k<H_;k+=8){
      float4 s1=ld4(&sxs[k]), s2=ld4(&sxs[k+4]);
      float4 x1=ld4(&hxs[k]), x2=ld4(&hxs[k+4]);
      gr =dot4(s1,ld4(wsr+k),gr );  gr =dot4(s2,ld4(wsr+k+4),gr );
      gz =dot4(s1,ld4(wsz+k),gz );  gz =dot4(s2,ld4(wsz+k+4),gz );
      gni=dot4(s1,ld4(wsn+k),gni);  gni=dot4(s2,ld4(wsn+k+4),gni);
      gr =dot4(x1,ld4(whr+k),gr );  gr =dot4(x2,ld4(whr+k+4),gr );
      gz =dot4(x1,ld4(whz+k),gz );  gz =dot4(x2,ld4(whz+k+4),gz );
      gnh=dot4(x1,ld4(whn+k),gnh);  gnh=dot4(x2,ld4(whn+k+4),gnh);
    }
    size_t gybase = (size_t)(b*TY_ + t)*G3_;
    float ir=bfu(Gy[gybase+u]), iz=bfu(Gy[gybase+H_+u]), inn=bfu(Gy[gybase+2*H_+u]);
    float r = sigm(ir+gr), z = sigm(iz+gz);
    float n = tanh_f(inn + gni + r*gnh);
    float hnew = (1.f-z)*n + z*hxs[u];
    float outv = hnew + sx;
    __syncthreads();
    hxs[u]=hnew; oxs[u]=hnew;
    Xfc[(size_t)(b*TY_+t)*H_ + u] = f2bf(outv);
    __syncthreads();
  }
}

extern "C" void kernel_launch(void* const* d_in, const int* in_sizes, int n_in,
                              void* d_out, int out_size, void* d_ws, size_t ws_size,
                              hipStream_t stream) {
  const int*   x     = (const int*)d_in[0];
  const int*   y     = (const int*)d_in[1];
  const float* emb   = (const float*)d_in[2];
  const float* eWih  = (const float*)d_in[3];
  const float* eWhh  = (const float*)d_in[4];
  const float* eBih  = (const float*)d_in[5];
  const float* eBhh  = (const float*)d_in[6];
  const float* dWih  = (const float*)d_in[7];
  const float* dWhh  = (const float*)d_in[8];
  const float* dBih  = (const float*)d_in[9];
  const float* dBhh  = (const float*)d_in[10];
  const float* hinit = (const float*)d_in[11];
  const float* fcW   = (const float*)d_in[12];
  const float* fcB   = (const float*)d_in[13];
  float* out = (float*)d_out;

  char* p = (char*)d_ws;
  auto take = [&](size_t bytes)->char*{ char* r = p; p += (bytes + 255) & ~(size_t)255; return r; };
  u16* Wfc_bf   = (u16*)take((size_t)V_*H_*2);        // 32000x512
  u16* ex_bf    = (u16*)take((size_t)B_*TX_*E_*2);    // 16384x256
  u16* Wih_bf   = (u16*)take((size_t)G3_*E_*2);       // 1536x256
  u16* Gx_bf    = (u16*)take((size_t)B_*TX_*G3_*2);   // 16384x1536
  u16* eh_bf    = (u16*)take((size_t)B_*TX_*H_*2);    // [b][t][u]
  u16* ehT_bf   = (u16*)take((size_t)B_*H_*TX_*2);    // [b][u][t]
  u16* embY_bf  = (u16*)take((size_t)4096*E_*2);      // 4064 rows used (padded)
  u16* dWihE_bf = (u16*)take((size_t)G3_*E_*2);       // dec_W_ih[:, :E]
  u16* Gy_bf    = (u16*)take((size_t)4096*G3_*2);     // 4064 rows used
  u16* Xfc_bf   = (u16*)take((size_t)4096*H_*2);      // 4064 rows used
  (void)ws_size; (void)in_sizes; (void)n_in; (void)out_size;

  // weight conversions
  cvt_rows<<<dim3(V_),  dim3(256), 0, stream>>>(fcW,  H_, 0, Wfc_bf,   H_);
  cvt_rows<<<dim3(G3_), dim3(256), 0, stream>>>(eWih, E_, 0, Wih_bf,   E_);
  cvt_rows<<<dim3(G3_), dim3(256), 0, stream>>>(dWih, E_+H_, 0, dWihE_bf, E_);

  // embedding gathers
  gather_embed<<<dim3(B_*TX_), dim3(E_), 0, stream>>>(emb, x, ex_bf, TX_, TX_);
  gather_embed<<<dim3(B_*TY_), dim3(E_), 0, stream>>>(emb, y, embY_bf, TY_, 128);

  // input-gate precomputes
  gemm_bf16<<<dim3(B_*TX_/128, G3_/128), dim3(256), 0, stream>>>(
      ex_bf, E_, Wih_bf, E_, Gx_bf, G3_, eBih, B_*TX_, E_, 1);
  gemm_bf16<<<dim3(32, G3_/128), dim3(256), 0, stream>>>(
      embY_bf, E_, dWihE_bf, E_, Gy_bf, G3_, dBih, B_*TY_, E_, 1);

  // sequential scans (per-batch persistent WGs)
  enc_kernel<<<dim3(B_), dim3(H_), 0, stream>>>(Gx_bf, eWhh, eBhh, eh_bf);
  transpose_eh<<<dim3(B_, TX_/64, H_/64), dim3(256), 0, stream>>>(eh_bf, ehT_bf);
  dec_kernel<<<dim3(B_), dim3(H_), 0, stream>>>(eh_bf, ehT_bf, Gy_bf, dWih, dWhh, dBhh, hinit, Xfc_bf);

  // final FC: (4064x512) @ (32000x512)^T + fc_b -> f32 d_out
  gemm_bf16<<<dim3(32, V_/128), dim3(256), 0, stream>>>(
      Xfc_bf, H_, Wfc_bf, H_, out, V_, fcB, B_*TY_, H_, 0);
}

// Round 5
// 11447.716 us; speedup vs baseline: 6.2534x; 6.2534x over previous
//
#include <hip/hip_runtime.h>
#include <hip/hip_bf16.h>

// Seq2Seq GRU+attention, MI355X. Round 5: register-resident recurrences.
// enc: 16 blocks, MFMA gates (M=32 batch), weights in VGPR B-frags, 1 grid
//      barrier per step (16-block sense-reversing, device-scope atomics).
// dec: 32 A-blocks (attention; eh[b] preloaded to 256 f32 VGPRs/wave) +
//      16 W-blocks (gsx+gh MFMA, both weight sets VGPR-resident),
//      flagA[b]/gen ping-pong. f32 h-state on the z*h blend path.

#define B_  32
#define TX_ 512
#define TY_ 127
#define E_  256
#define H_  512
#define G3_ 1536
#define V_  32000

typedef unsigned short u16;
typedef short short8 __attribute__((ext_vector_type(8)));
typedef float f32x4 __attribute__((ext_vector_type(4)));

// ctrl layout (ints): [0,1]=encCnt [2]=encGen [3,4]=decCnt [5]=decGen [8..39]=flagA
#define C_ENCCNT 0
#define C_ENCGEN 2
#define C_DECCNT 3
#define C_DECGEN 5
#define C_FLAGA  8

__device__ __forceinline__ float bfu(u16 h){ union{unsigned u; float f;} x; x.u=((unsigned)h)<<16; return x.f; }
__device__ __forceinline__ float bflo(unsigned p){ union{unsigned u; float f;} x; x.u=p<<16; return x.f; }
__device__ __forceinline__ float bfhi(unsigned p){ union{unsigned u; float f;} x; x.u=p&0xffff0000u; return x.f; }
__device__ __forceinline__ u16 f2bf(float f){ union{float f; unsigned u;} v; v.f=f; unsigned r=v.u+0x7fffu+((v.u>>16)&1u); return (u16)(r>>16); }
__device__ __forceinline__ float sigm(float x){ return 1.f/(1.f+__expf(-x)); }
__device__ __forceinline__ float tanh_f(float x){ return 1.f - 2.f/(__expf(2.f*x)+1.f); }

__device__ __forceinline__ void spin_ge(int* p, int target){
  int n = 0;
  while (__hip_atomic_load(p, __ATOMIC_ACQUIRE, __HIP_MEMORY_SCOPE_AGENT) < target){
    __builtin_amdgcn_s_sleep(1);
    if (++n > (1<<20)) break;   // bounded: deadlock -> wrong output, not hang
  }
}

// sense-reversing barrier over n blocks; tid0 arrives/spins, block-wide sync.
__device__ __forceinline__ void wbarrier(int* cnt2, int* gen, int target, int n){
  __syncthreads();
  if (threadIdx.x == 0){
    __threadfence();
    int par = target & 1;
    int old = __hip_atomic_fetch_add(&cnt2[par], 1, __ATOMIC_ACQ_REL, __HIP_MEMORY_SCOPE_AGENT);
    if (old == n-1){
      __hip_atomic_store(&cnt2[par], 0, __ATOMIC_RELAXED, __HIP_MEMORY_SCOPE_AGENT);
      __hip_atomic_store(gen, target, __ATOMIC_RELEASE, __HIP_MEMORY_SCOPE_AGENT);
    } else {
      spin_ge(gen, target);
    }
  }
  __syncthreads();
}

// ---------- f32 -> bf16 row converter (strided source rows) ----------
__global__ void cvt_rows(const float* __restrict__ src, int sld, int soff,
                         u16* __restrict__ dst, int cols){
  int r = blockIdx.x;
  const float* s = src + (size_t)r*sld + soff;
  u16* d = dst + (size_t)r*cols;
  for (int c = threadIdx.x; c < cols; c += blockDim.x) d[c] = f2bf(s[c]);
}

// ---------- embedding gather -> bf16 rows ----------
__global__ void gather_embed(const float* __restrict__ emb, const int* __restrict__ idx,
                             u16* __restrict__ dst, int rows_per_b, int ld){
  int m = blockIdx.x;
  int bb = m / rows_per_b, tt = m - bb*rows_per_b;
  int id = idx[bb*ld + tt];
  dst[(size_t)m*E_ + threadIdx.x] = f2bf(emb[(size_t)id*E_ + threadIdx.x]);
}

// ---------- bf16 MFMA GEMM: C[M,N] = A[M,K] @ B[N,K]^T + bias ----------
__global__ __launch_bounds__(256) void gemm_bf16(
    const u16* __restrict__ A, int lda, const u16* __restrict__ Bm, int ldb,
    void* __restrict__ Cout, int ldc, const float* __restrict__ bias,
    int M, int K, int out_bf16)
{
  int wave = threadIdx.x >> 6, lane = threadIdx.x & 63;
  int m0 = blockIdx.x*128 + (wave>>1)*64;
  int n0 = blockIdx.y*128 + (wave&1)*64;
  int lr = lane & 15, lk = (lane>>4)*8;
  f32x4 acc[4][4];
  #pragma unroll
  for (int i=0;i<4;++i)
    #pragma unroll
    for (int j=0;j<4;++j) acc[i][j] = (f32x4){0.f,0.f,0.f,0.f};

  for (int k0=0; k0<K; k0+=32){
    short8 af[4], bfv[4];
    #pragma unroll
    for (int i=0;i<4;++i){
      int row = m0 + i*16 + lr; if (row > M-1) row = M-1;
      af[i] = *(const short8*)(A + (size_t)row*lda + k0 + lk);
    }
    #pragma unroll
    for (int j=0;j<4;++j){
      int col = n0 + j*16 + lr;
      bfv[j] = *(const short8*)(Bm + (size_t)col*ldb + k0 + lk);
    }
    #pragma unroll
    for (int i=0;i<4;++i)
      #pragma unroll
      for (int j=0;j<4;++j)
        acc[i][j] = __builtin_amdgcn_mfma_f32_16x16x32_bf16(af[i], bfv[j], acc[i][j], 0,0,0);
  }
  int rbase = (lane>>4)*4;
  #pragma unroll
  for (int i=0;i<4;++i){
    #pragma unroll
    for (int r=0;r<4;++r){
      int row = m0 + i*16 + rbase + r;
      if (row < M){
        #pragma unroll
        for (int j=0;j<4;++j){
          int col = n0 + j*16 + lr;
          float v = acc[i][j][r] + bias[col];
          if (out_bf16) ((u16*)Cout)[(size_t)row*ldc + col] = f2bf(v);
          else          ((float*)Cout)[(size_t)row*ldc + col] = v;
        }
      }
    }
  }
}

// ---------- encoder: 16 blocks x 1024 thr; block g owns units [32g,32g+32) ----------
__global__ __launch_bounds__(1024,4) void enc_step(
    const u16* __restrict__ Gx, const u16* __restrict__ Whh_bf,
    const float* __restrict__ bhh, u16* __restrict__ eh,
    u16* __restrict__ hgd, float* __restrict__ h32, int* ctrl)
{
  struct EShm { u16 stgl[32][520]; float gH[32][100]; };
  __shared__ __align__(16) char smem_[sizeof(EShm)];
  EShm& S = *(EShm*)smem_;
  int tid = threadIdx.x, g = blockIdx.x;
  int wave = tid>>6, lane = tid&63;
  int pb = tid>>5, pu = tid&31, u = g*32 + pu;

  // B-fragments: wave<12 covers (mt 0..1) x (nt 0..5); nt: 0,1=r 2,3=z 4,5=n
  short8 fH[16];
  int mt = wave/6, nt = wave%6;
  if (wave < 12){
    int gate = nt>>1, h16 = (nt&1)*16;
    int row = gate*H_ + g*32 + h16 + (lane&15), kb = (lane>>4)*8;
    #pragma unroll
    for (int ks=0;ks<16;++ks)
      fH[ks] = *(const short8*)(Whh_bf + (size_t)row*H_ + ks*32 + kb);
  }
  float bhR = bhh[u], bhZ = bhh[u+H_], bhN = bhh[u+2*H_];

  // zero h (parity 0 bf16 + f32 state), then init barrier (gen=1)
  hgd[(size_t)pb*H_ + u] = 0;
  h32[(size_t)pb*H_ + u] = 0.f;
  wbarrier(&ctrl[C_ENCCNT], &ctrl[C_ENCGEN], 1, 16);

  for (int t=0;t<TX_;++t){
    { // stage h (parity t&1) -> LDS [32][520]
      const u16* src = hgd + (size_t)(t&1)*B_*H_;
      int f = tid*16, row = f>>9, col = f&511;
      *(uint4*)&S.stgl[row][col]   = *(const uint4*)(src + (size_t)row*H_ + col);
      *(uint4*)&S.stgl[row][col+8] = *(const uint4*)(src + (size_t)row*H_ + col + 8);
    }
    __syncthreads();
    if (wave < 12){
      f32x4 acc = (f32x4){0.f,0.f,0.f,0.f};
      int ar = mt*16 + (lane&15), ak = (lane>>4)*8;
      #pragma unroll
      for (int ks=0;ks<16;++ks){
        short8 af = *(const short8*)&S.stgl[ar][ks*32 + ak];
        acc = __builtin_amdgcn_mfma_f32_16x16x32_bf16(af, fH[ks], acc, 0,0,0);
      }
      int drow = mt*16 + ((lane>>4)<<2), dcol = nt*16 + (lane&15);
      #pragma unroll
      for (int r=0;r<4;++r) S.gH[drow+r][dcol] = acc[r];
    }
    __syncthreads();
    // pointwise GRU for (batch pb, unit u)
    size_t gxb = ((size_t)pb*TX_ + t)*G3_;
    float iR = bfu(Gx[gxb+u]), iZ = bfu(Gx[gxb+H_+u]), iN = bfu(Gx[gxb+2*H_+u]);
    float ghR = S.gH[pb][pu], ghZ = S.gH[pb][32+pu], ghN = S.gH[pb][64+pu];
    float r = sigm(iR + ghR + bhR), z = sigm(iZ + ghZ + bhZ);
    float n = tanh_f(iN + r*(ghN + bhN));
    float hold = h32[(size_t)pb*H_ + u];
    float hnew = (1.f-z)*n + z*hold;
    h32[(size_t)pb*H_ + u] = hnew;
    hgd[(size_t)((t+1)&1)*B_*H_ + pb*H_ + u] = f2bf(hnew);
    eh[((size_t)pb*TX_ + t)*H_ + u] = f2bf(hnew);
    wbarrier(&ctrl[C_ENCCNT], &ctrl[C_ENCGEN], t+2, 16);
  }
}

// ---------- decoder: 48 blocks x 1024 thr (32 A-blocks + 16 W-blocks) ----------
__global__ __launch_bounds__(1024,4) void dec_step(
    const u16* __restrict__ eh, const u16* __restrict__ Gy,
    const u16* __restrict__ WihS_bf, const u16* __restrict__ Whh_bf,
    const float* __restrict__ dbhh, const float* __restrict__ hinit,
    float* __restrict__ sxf, u16* __restrict__ sxb,
    u16* __restrict__ hdd, float* __restrict__ h32d,
    u16* __restrict__ Xfc, int* ctrl)
{
  struct AShm { float oxl[512]; float sc[512]; float a[512]; float red[32]; float sxp[16][516]; };
  struct WShm { u16 stgl[32][520]; float gS[32][100]; float gH[32][100]; };
  __shared__ __align__(16) char smem_[sizeof(WShm)];
  int tid = threadIdx.x;
  int wave = tid>>6, lane = tid&63;

  if (blockIdx.x < 32){
    // ===== role A: attention for batch b =====
    AShm& S = *(AShm*)smem_;
    int b = blockIdx.x;
    // preload eh[b] rows (wave w owns t' in [32w,32w+32)) as f32 regs
    float er[32][8];
    {
      const u16* ehp = eh + ((size_t)b*TX_ + wave*32)*H_ + lane*8;
      #pragma unroll
      for (int i=0;i<32;++i){
        uint4 v = *(const uint4*)(ehp + (size_t)i*H_);
        er[i][0]=bflo(v.x); er[i][1]=bfhi(v.x); er[i][2]=bflo(v.y); er[i][3]=bfhi(v.y);
        er[i][4]=bflo(v.z); er[i][5]=bfhi(v.z); er[i][6]=bflo(v.w); er[i][7]=bfhi(v.w);
      }
    }
    for (int t=0;t<TY_;++t){
      if (t > 0){
        if (tid==0) spin_ge(&ctrl[C_DECGEN], t+1);
        __syncthreads();
      }
      if (tid < H_) S.oxl[tid] = (t==0) ? hinit[tid] : h32d[(size_t)b*H_ + tid];
      __syncthreads();
      // scores[t'] = dot(eh[b][t'], ox)
      float ox8[8];
      #pragma unroll
      for (int j=0;j<8;++j) ox8[j] = S.oxl[lane*8+j];
      #pragma unroll
      for (int i=0;i<32;++i){
        float p = er[i][0]*ox8[0]+er[i][1]*ox8[1]+er[i][2]*ox8[2]+er[i][3]*ox8[3]
                + er[i][4]*ox8[4]+er[i][5]*ox8[5]+er[i][6]*ox8[6]+er[i][7]*ox8[7];
        #pragma unroll
        for (int o=32;o>0;o>>=1) p += __shfl_xor(p, o);
        if (lane==0) S.sc[wave*32+i] = p;
      }
      __syncthreads();
      // softmax over 512 (threads<512 active; syncs block-uniform)
      {
        float v = (tid<H_) ? S.sc[tid] : -1e30f;
        float m = v;
        #pragma unroll
        for (int o=32;o>0;o>>=1) m = fmaxf(m, __shfl_xor(m, o));
        if ((tid&63)==0) S.red[tid>>6] = m;
        __syncthreads();
        if (tid==0){
          float mm = S.red[0];
          for (int w=1;w<8;++w) mm = fmaxf(mm, S.red[w]);
          S.red[16] = mm;
        }
        __syncthreads();
        float M = S.red[16];
        float p = (tid<H_) ? __expf(v - M) : 0.f;
        float s = p;
        #pragma unroll
        for (int o=32;o>0;o>>=1) s += __shfl_xor(s, o);
        if ((tid&63)==0) S.red[tid>>6] = s;
        __syncthreads();
        if (tid==0){
          float ss=0.f; for (int w=0;w<8;++w) ss += S.red[w];
          S.red[17] = 1.f/ss;
        }
        __syncthreads();
        if (tid<H_) S.a[tid] = p * S.red[17];
      }
      __syncthreads();
      // sx[u] = sum_t' a[t'] * eh[t'][u]  (per-wave partials from regs)
      float sx8[8] = {0,0,0,0,0,0,0,0};
      int t0 = wave*32;
      #pragma unroll
      for (int i=0;i<32;++i){
        float ai = S.a[t0+i];
        #pragma unroll
        for (int j=0;j<8;++j) sx8[j] = fmaf(ai, er[i][j], sx8[j]);
      }
      #pragma unroll
      for (int j=0;j<8;++j) S.sxp[wave][lane*8+j] = sx8[j];
      __syncthreads();
      if (tid < H_){
        float s = 0.f;
        #pragma unroll
        for (int w=0;w<16;++w) s += S.sxp[w][tid];
        sxf[(size_t)b*H_ + tid] = s;
        sxb[(size_t)b*H_ + tid] = f2bf(s);
      }
      __syncthreads();
      if (tid==0){
        __threadfence();
        __hip_atomic_store(&ctrl[C_FLAGA + b], t+1, __ATOMIC_RELEASE, __HIP_MEMORY_SCOPE_AGENT);
      }
    }
  } else {
    // ===== role W: gates+GRU for unit slice g =====
    WShm& S = *(WShm*)smem_;
    int g = blockIdx.x - 32;
    int pb = tid>>5, pu = tid&31, u = g*32 + pu;
    short8 fS[16], fH[16];
    int mt = wave/6, nt = wave%6;
    if (wave < 12){
      int gate = nt>>1, h16 = (nt&1)*16;
      int row = gate*H_ + g*32 + h16 + (lane&15), kb = (lane>>4)*8;
      #pragma unroll
      for (int ks=0;ks<16;++ks){
        fS[ks] = *(const short8*)(WihS_bf + (size_t)row*H_ + ks*32 + kb);
        fH[ks] = *(const short8*)(Whh_bf  + (size_t)row*H_ + ks*32 + kb);
      }
    }
    float bhR = dbhh[u], bhZ = dbhh[u+H_], bhN = dbhh[u+2*H_];
    hdd[(size_t)pb*H_ + u] = 0;        // parity 0
    h32d[(size_t)pb*H_ + u] = 0.f;
    wbarrier(&ctrl[C_DECCNT], &ctrl[C_DECGEN], 1, 16);

    for (int t=0;t<TY_;++t){
      if (tid < 32) spin_ge(&ctrl[C_FLAGA + tid], t+1);
      __syncthreads();
      { // stage sx (bf16) -> stgl
        int f = tid*16, row = f>>9, col = f&511;
        *(uint4*)&S.stgl[row][col]   = *(const uint4*)(sxb + (size_t)row*H_ + col);
        *(uint4*)&S.stgl[row][col+8] = *(const uint4*)(sxb + (size_t)row*H_ + col + 8);
      }
      __syncthreads();
      f32x4 accS = (f32x4){0.f,0.f,0.f,0.f}, accH = (f32x4){0.f,0.f,0.f,0.f};
      int ar = mt*16 + (lane&15), ak = (lane>>4)*8;
      if (wave < 12){
        #pragma unroll
        for (int ks=0;ks<16;++ks){
          short8 af = *(const short8*)&S.stgl[ar][ks*32 + ak];
          accS = __builtin_amdgcn_mfma_f32_16x16x32_bf16(af, fS[ks], accS, 0,0,0);
        }
      }
      __syncthreads();   // stgl reuse
      { // stage hx (parity t&1) -> stgl
        const u16* src = hdd + (size_t)(t&1)*B_*H_;
        int f = tid*16, row = f>>9, col = f&511;
        *(uint4*)&S.stgl[row][col]   = *(const uint4*)(src + (size_t)row*H_ + col);
        *(uint4*)&S.stgl[row][col+8] = *(const uint4*)(src + (size_t)row*H_ + col + 8);
      }
      __syncthreads();
      if (wave < 12){
        #pragma unroll
        for (int ks=0;ks<16;++ks){
          short8 af = *(const short8*)&S.stgl[ar][ks*32 + ak];
          accH = __builtin_amdgcn_mfma_f32_16x16x32_bf16(af, fH[ks], accH, 0,0,0);
        }
        int drow = mt*16 + ((lane>>4)<<2), dcol = nt*16 + (lane&15);
        #pragma unroll
        for (int r=0;r<4;++r){ S.gS[drow+r][dcol] = accS[r]; S.gH[drow+r][dcol] = accH[r]; }
      }
      __syncthreads();
      // pointwise: i_n gets gsx UNSCALED; only gh_n (+bhh_n) is r-scaled
      size_t gyb = ((size_t)pb*TY_ + t)*G3_;
      float iR = bfu(Gy[gyb+u]), iZ = bfu(Gy[gyb+H_+u]), iN = bfu(Gy[gyb+2*H_+u]);
      float gsR = S.gS[pb][pu],    ghR = S.gH[pb][pu];
      float gsZ = S.gS[pb][32+pu], ghZ = S.gH[pb][32+pu];
      float gsN = S.gS[pb][64+pu], ghN = S.gH[pb][64+pu];
      float r = sigm(iR + gsR + ghR + bhR);
      float z = sigm(iZ + gsZ + ghZ + bhZ);
      float n = tanh_f(iN + gsN + r*(ghN + bhN));
      float hold = h32d[(size_t)pb*H_ + u];
      float hnew = (1.f-z)*n + z*hold;
      h32d[(size_t)pb*H_ + u] = hnew;
      hdd[(size_t)((t+1)&1)*B_*H_ + pb*H_ + u] = f2bf(hnew);
      float sxv = sxf[(size_t)pb*H_ + u];
      Xfc[((size_t)pb*TY_ + t)*H_ + u] = f2bf(hnew + sxv);
      wbarrier(&ctrl[C_DECCNT], &ctrl[C_DECGEN], t+2, 16);
    }
  }
}

extern "C" void kernel_launch(void* const* d_in, const int* in_sizes, int n_in,
                              void* d_out, int out_size, void* d_ws, size_t ws_size,
                              hipStream_t stream) {
  const int*   x     = (const int*)d_in[0];
  const int*   y     = (const int*)d_in[1];
  const float* emb   = (const float*)d_in[2];
  const float* eWih  = (const float*)d_in[3];
  const float* eWhh  = (const float*)d_in[4];
  const float* eBih  = (const float*)d_in[5];
  const float* eBhh  = (const float*)d_in[6];
  const float* dWih  = (const float*)d_in[7];
  const float* dWhh  = (const float*)d_in[8];
  const float* dBih  = (const float*)d_in[9];
  const float* dBhh  = (const float*)d_in[10];
  const float* hinit = (const float*)d_in[11];
  const float* fcW   = (const float*)d_in[12];
  const float* fcB   = (const float*)d_in[13];
  float* out = (float*)d_out;
  (void)in_sizes; (void)n_in; (void)out_size; (void)ws_size;

  char* p = (char*)d_ws;
  auto take = [&](size_t bytes)->char*{ char* r = p; p += (bytes + 255) & ~(size_t)255; return r; };
  u16* Wfc_bf   = (u16*)take((size_t)V_*H_*2);
  u16* ex_bf    = (u16*)take((size_t)B_*TX_*E_*2);
  u16* eWih_bf  = (u16*)take((size_t)G3_*E_*2);
  u16* Gx_bf    = (u16*)take((size_t)B_*TX_*G3_*2);
  u16* eh_bf    = (u16*)take((size_t)B_*TX_*H_*2);
  u16* embY_bf  = (u16*)take((size_t)4096*E_*2);
  u16* dWihE_bf = (u16*)take((size_t)G3_*E_*2);
  u16* Gy_bf    = (u16*)take((size_t)4096*G3_*2);
  u16* Xfc_bf   = (u16*)take((size_t)4096*H_*2);
  u16* eWhh_bf  = (u16*)take((size_t)G3_*H_*2);
  u16* dWhh_bf  = (u16*)take((size_t)G3_*H_*2);
  u16* dWihS_bf = (u16*)take((size_t)G3_*H_*2);
  u16* hgd      = (u16*)take((size_t)2*B_*H_*2);
  float* h32e   = (float*)take((size_t)B_*H_*4);
  u16* hdd      = (u16*)take((size_t)2*B_*H_*2);
  float* h32d   = (float*)take((size_t)B_*H_*4);
  float* sxf    = (float*)take((size_t)B_*H_*4);
  u16* sxb      = (u16*)take((size_t)B_*H_*2);
  int* ctrl     = (int*)take(256);

  hipMemsetAsync(ctrl, 0, 256, stream);

  // weight conversions
  cvt_rows<<<dim3(V_),  dim3(256), 0, stream>>>(fcW,  H_, 0, Wfc_bf,   H_);
  cvt_rows<<<dim3(G3_), dim3(256), 0, stream>>>(eWih, E_, 0, eWih_bf,  E_);
  cvt_rows<<<dim3(G3_), dim3(256), 0, stream>>>(dWih, E_+H_, 0, dWihE_bf, E_);
  cvt_rows<<<dim3(G3_), dim3(256), 0, stream>>>(eWhh, H_, 0, eWhh_bf,  H_);
  cvt_rows<<<dim3(G3_), dim3(256), 0, stream>>>(dWhh, H_, 0, dWhh_bf,  H_);
  cvt_rows<<<dim3(G3_), dim3(256), 0, stream>>>(dWih, E_+H_, E_, dWihS_bf, H_);

  // embedding gathers
  gather_embed<<<dim3(B_*TX_), dim3(E_), 0, stream>>>(emb, x, ex_bf, TX_, TX_);
  gather_embed<<<dim3(B_*TY_), dim3(E_), 0, stream>>>(emb, y, embY_bf, TY_, 128);

  // input-gate precomputes
  gemm_bf16<<<dim3(B_*TX_/128, G3_/128), dim3(256), 0, stream>>>(
      ex_bf, E_, eWih_bf, E_, Gx_bf, G3_, eBih, B_*TX_, E_, 1);
  gemm_bf16<<<dim3(32, G3_/128), dim3(256), 0, stream>>>(
      embY_bf, E_, dWihE_bf, E_, Gy_bf, G3_, dBih, B_*TY_, E_, 1);

  // sequential scans
  enc_step<<<dim3(16), dim3(1024), 0, stream>>>(Gx_bf, eWhh_bf, eBhh, eh_bf, hgd, h32e, ctrl);
  dec_step<<<dim3(48), dim3(1024), 0, stream>>>(eh_bf, Gy_bf, dWihS_bf, dWhh_bf, dBhh, hinit,
                                                sxf, sxb, hdd, h32d, Xfc_bf, ctrl);

  // final FC
  gemm_bf16<<<dim3(32, V_/128), dim3(256), 0, stream>>>(
      Xfc_bf, H_, Wfc_bf, H_, out, V_, fcB, B_*TY_, H_, 0);
}

// Round 7
// 8508.401 us; speedup vs baseline: 8.4136x; 1.3455x over previous
//
#include <hip/hip_runtime.h>
#include <hip/hip_bf16.h>

// Seq2Seq GRU+attention, MI355X. Round 7: identical to round-6 submission
// (infra failure, no signal). 512-thr blocks (256-VGPR budget, no spill),
// relaxed-poll flag barriers, MFMA everywhere.

#define B_  32
#define TX_ 512
#define TY_ 127
#define E_  256
#define H_  512
#define G3_ 1536
#define V_  32000

typedef unsigned short u16;
typedef short short8 __attribute__((ext_vector_type(8)));
typedef float f32x4 __attribute__((ext_vector_type(4)));

__device__ __forceinline__ float bfu(u16 h){ union{unsigned u; float f;} x; x.u=((unsigned)h)<<16; return x.f; }
__device__ __forceinline__ u16 f2bf(float f){ union{float f; unsigned u;} v; v.f=f; unsigned r=v.u+0x7fffu+((v.u>>16)&1u); return (u16)(r>>16); }
__device__ __forceinline__ float sigm(float x){ return 1.f/(1.f+__expf(-x)); }
__device__ __forceinline__ float tanh_f(float x){ return 1.f - 2.f/(__expf(2.f*x)+1.f); }

// flag barrier over 32 blocks: arrive = release own flag; wait = 32 lanes
// poll 32 flags with RELAXED loads (no cache-inv), one ACQUIRE at the end.
__device__ __forceinline__ void flagbar(int* flags, int target){
  __syncthreads();
  if (threadIdx.x == 0)
    __hip_atomic_store(&flags[blockIdx.x], target, __ATOMIC_RELEASE, __HIP_MEMORY_SCOPE_AGENT);
  if (threadIdx.x < 32){
    int n = 0;
    while (__hip_atomic_load(&flags[threadIdx.x], __ATOMIC_RELAXED, __HIP_MEMORY_SCOPE_AGENT) < target){
      __builtin_amdgcn_s_sleep(2);
      if (++n > (1<<22)) break;   // bounded: bug -> wrong output, not hang
    }
    (void)__hip_atomic_load(&flags[threadIdx.x], __ATOMIC_ACQUIRE, __HIP_MEMORY_SCOPE_AGENT);
  }
  __syncthreads();
}

// ---------- f32 -> bf16 row converter ----------
__global__ void cvt_rows(const float* __restrict__ src, int sld, int soff,
                         u16* __restrict__ dst, int cols){
  int r = blockIdx.x;
  const float* s = src + (size_t)r*sld + soff;
  u16* d = dst + (size_t)r*cols;
  for (int c = threadIdx.x; c < cols; c += blockDim.x) d[c] = f2bf(s[c]);
}

// ---------- embedding gather -> bf16 rows ----------
__global__ void gather_embed(const float* __restrict__ emb, const int* __restrict__ idx,
                             u16* __restrict__ dst, int rows_per_b, int ld){
  int m = blockIdx.x;
  int bb = m / rows_per_b, tt = m - bb*rows_per_b;
  int id = idx[bb*ld + tt];
  dst[(size_t)m*E_ + threadIdx.x] = f2bf(emb[(size_t)id*E_ + threadIdx.x]);
}

// ---------- bf16 MFMA GEMM: C[M,N] = A[M,K] @ B[N,K]^T + bias ----------
__global__ __launch_bounds__(256) void gemm_bf16(
    const u16* __restrict__ A, int lda, const u16* __restrict__ Bm, int ldb,
    void* __restrict__ Cout, int ldc, const float* __restrict__ bias,
    int M, int K, int out_bf16)
{
  int wave = threadIdx.x >> 6, lane = threadIdx.x & 63;
  int m0 = blockIdx.x*128 + (wave>>1)*64;
  int n0 = blockIdx.y*128 + (wave&1)*64;
  int lr = lane & 15, lk = (lane>>4)*8;
  f32x4 acc[4][4];
  #pragma unroll
  for (int i=0;i<4;++i)
    #pragma unroll
    for (int j=0;j<4;++j) acc[i][j] = (f32x4){0.f,0.f,0.f,0.f};
  for (int k0=0; k0<K; k0+=32){
    short8 af[4], bfv[4];
    #pragma unroll
    for (int i=0;i<4;++i){
      int row = m0 + i*16 + lr; if (row > M-1) row = M-1;
      af[i] = *(const short8*)(A + (size_t)row*lda + k0 + lk);
    }
    #pragma unroll
    for (int j=0;j<4;++j){
      int col = n0 + j*16 + lr;
      bfv[j] = *(const short8*)(Bm + (size_t)col*ldb + k0 + lk);
    }
    #pragma unroll
    for (int i=0;i<4;++i)
      #pragma unroll
      for (int j=0;j<4;++j)
        acc[i][j] = __builtin_amdgcn_mfma_f32_16x16x32_bf16(af[i], bfv[j], acc[i][j], 0,0,0);
  }
  int rbase = (lane>>4)*4;
  #pragma unroll
  for (int i=0;i<4;++i)
    #pragma unroll
    for (int r=0;r<4;++r){
      int row = m0 + i*16 + rbase + r;
      if (row < M){
        #pragma unroll
        for (int j=0;j<4;++j){
          int col = n0 + j*16 + lr;
          float v = acc[i][j][r] + bias[col];
          if (out_bf16) ((u16*)Cout)[(size_t)row*ldc + col] = f2bf(v);
          else          ((float*)Cout)[(size_t)row*ldc + col] = v;
        }
      }
    }
}

// ---------- eh[b][t][u] -> ehT[b][u][t] (proven round-4) ----------
__global__ __launch_bounds__(256) void transpose_eh(const u16* __restrict__ eh, u16* __restrict__ ehT){
  int b = blockIdx.x, tb = blockIdx.y, ub = blockIdx.z;
  __shared__ u16 tile[64][65];
  int c = threadIdx.x & 63, r0 = threadIdx.x >> 6;
  const u16* src = eh + (size_t)b*TX_*H_;
  #pragma unroll
  for (int r=r0; r<64; r+=4) tile[r][c] = src[(size_t)(tb*64+r)*H_ + ub*64 + c];
  __syncthreads();
  u16* dst = ehT + (size_t)b*H_*TX_;
  #pragma unroll
  for (int r=r0; r<64; r+=4) dst[(size_t)(ub*64+r)*TX_ + tb*64 + c] = tile[c][r];
}

// stage [32][512] bf16 global -> stgl[32][520] LDS (512 threads, 4 uint4 each)
#define STAGE32x512(SRC) do { \
  _Pragma("unroll") \
  for (int c_=0;c_<4;++c_){ \
    int idx_ = threadIdx.x + c_*512; \
    int row_ = idx_>>6, col_ = (idx_&63)*8; \
    *(uint4*)&stgl[row_][col_] = *(const uint4*)((SRC) + (size_t)row_*H_ + col_); \
  } \
} while(0)

// ---------- encoder: 32 blocks x 512 thr; block g owns units [16g,16g+16) ----------
__global__ __launch_bounds__(512,2) void enc_v2(
    const u16* __restrict__ Gx, const u16* __restrict__ Whh_bf,
    const float* __restrict__ bhh, u16* __restrict__ eh,
    u16* __restrict__ hgd, int* flags)
{
  __shared__ __align__(16) u16 stgl[32][520];
  __shared__ __align__(16) float gH[32][52];
  int tid = threadIdx.x, g = blockIdx.x;
  int wave = tid>>6, lane = tid&63;
  int pb = tid>>4, pu = tid&15, u = g*16 + pu;

  // B-frags: waves 0..5 = (mt,nt) = (wave/3, wave%3); nt = gate (r,z,n)
  short8 fH[16];
  int mt = wave/3, nt = wave%3;
  if (wave < 6){
    int row = nt*H_ + g*16 + (lane&15);
    int kb = (lane>>4)*8;
    #pragma unroll
    for (int ks=0;ks<16;++ks)
      fH[ks] = *(const short8*)(Whh_bf + (size_t)row*H_ + ks*32 + kb);
  }
  float bhR = bhh[u], bhZ = bhh[u+H_], bhN = bhh[u+2*H_];
  float hloc = 0.f;                 // h for (batch pb, unit u), f32 resident

  for (int t=0;t<TX_;++t){
    STAGE32x512(hgd + (size_t)(t&1)*B_*H_);
    __syncthreads();
    if (wave < 6){
      f32x4 acc = (f32x4){0.f,0.f,0.f,0.f};
      int ar = mt*16 + (lane&15), ak = (lane>>4)*8;
      #pragma unroll
      for (int ks=0;ks<16;++ks)
        acc = __builtin_amdgcn_mfma_f32_16x16x32_bf16(*(const short8*)&stgl[ar][ks*32+ak], fH[ks], acc, 0,0,0);
      int dr = mt*16 + ((lane>>4)<<2), dc = nt*16 + (lane&15);
      #pragma unroll
      for (int r=0;r<4;++r) gH[dr+r][dc] = acc[r];
    }
    __syncthreads();
    size_t gxb = ((size_t)pb*TX_ + t)*G3_;
    float iR = bfu(Gx[gxb+u]), iZ = bfu(Gx[gxb+H_+u]), iN = bfu(Gx[gxb+2*H_+u]);
    float r = sigm(iR + gH[pb][pu]     + bhR);
    float z = sigm(iZ + gH[pb][16+pu]  + bhZ);
    float n = tanh_f(iN + r*(gH[pb][32+pu] + bhN));
    hloc = (1.f-z)*n + z*hloc;
    u16 hb = f2bf(hloc);
    hgd[(size_t)((t+1)&1)*B_*H_ + pb*H_ + u] = hb;
    eh[((size_t)pb*TX_ + t)*H_ + u] = hb;
    flagbar(flags, t+1);
  }
}

// ---------- decoder: 32 blocks x 512 thr ----------
// block g: phase A = attention for batch g (MFMA scores + MFMA PV);
//          phase W = gates for units [16g,16g+16) over all 32 batches (M=32).
__global__ __launch_bounds__(512,2) void dec_v2(
    const u16* __restrict__ eh, const u16* __restrict__ ehT,
    const u16* __restrict__ Gy,
    const u16* __restrict__ WihS_bf, const u16* __restrict__ Whh_bf,
    const float* __restrict__ dbhh, const float* __restrict__ hinit,
    float* __restrict__ sxf, u16* __restrict__ sxb,
    u16* __restrict__ hdd, u16* __restrict__ Xfc,
    int* flags1, int* flags2)
{
  __shared__ __align__(16) u16 stgl[32][520];
  __shared__ __align__(16) float gS[32][52], gH[32][52];
  __shared__ __align__(16) u16 oxb[520], ab[520];
  __shared__ __align__(16) float sc[512];
  __shared__ float red[32];
  int tid = threadIdx.x, g = blockIdx.x;
  int wave = tid>>6, lane = tid&63;
  int pb = tid>>4, pu = tid&15, u = g*16 + pu;

  short8 fS[16], fH[16];
  int mt = wave/3, nt = wave%3;
  if (wave < 6){
    int row = nt*H_ + g*16 + (lane&15);
    int kb = (lane>>4)*8;
    #pragma unroll
    for (int ks=0;ks<16;++ks){
      fS[ks] = *(const short8*)(WihS_bf + (size_t)row*H_ + ks*32 + kb);
      fH[ks] = *(const short8*)(Whh_bf  + (size_t)row*H_ + ks*32 + kb);
    }
  }
  float bhR = dbhh[u], bhZ = dbhh[u+H_], bhN = dbhh[u+2*H_];
  float hloc = 0.f;
  const u16* ehg  = eh  + (size_t)g*TX_*H_;
  const u16* ehTg = ehT + (size_t)g*H_*TX_;
  bool bl = (lane&15) == 0;

  for (int t=0;t<TY_;++t){
    int par = t&1;
    // ===== phase A: attention for batch g =====
    oxb[tid] = (t==0) ? f2bf(hinit[tid]) : hdd[(size_t)par*B_*H_ + g*H_ + tid];
    __syncthreads();
    // scores[t'] for rows [64*wave, 64*wave+64): D-col0 = eh_rows @ ox
    {
      f32x4 acS[4];
      #pragma unroll
      for (int i=0;i<4;++i) acS[i] = (f32x4){0.f,0.f,0.f,0.f};
      #pragma unroll
      for (int kt=0;kt<16;++kt){
        short8 bf = (short8){0,0,0,0,0,0,0,0};
        if (bl) bf = *(const short8*)&oxb[kt*32 + (lane>>4)*8];
        #pragma unroll
        for (int m2=0;m2<4;++m2){
          short8 af = *(const short8*)(ehg + (size_t)(wave*64 + m2*16 + (lane&15))*H_ + kt*32 + (lane>>4)*8);
          acS[m2] = __builtin_amdgcn_mfma_f32_16x16x32_bf16(af, bf, acS[m2], 0,0,0);
        }
      }
      if (bl){
        #pragma unroll
        for (int m2=0;m2<4;++m2)
          #pragma unroll
          for (int r=0;r<4;++r)
            sc[wave*64 + m2*16 + (lane>>4)*4 + r] = acS[m2][r];
      }
    }
    __syncthreads();
    // softmax over 512 scores
    {
      float v = sc[tid];
      float m = v;
      #pragma unroll
      for (int o=32;o>0;o>>=1) m = fmaxf(m, __shfl_xor(m, o));
      if (lane==0) red[wave] = m;
      __syncthreads();
      if (tid==0){
        float mm = red[0];
        for (int w=1;w<8;++w) mm = fmaxf(mm, red[w]);
        red[16] = mm;
      }
      __syncthreads();
      float M = red[16];
      float p = __expf(v - M);
      float s = p;
      #pragma unroll
      for (int o=32;o>0;o>>=1) s += __shfl_xor(s, o);
      if (lane==0) red[wave] = s;
      __syncthreads();
      if (tid==0){
        float ss = 0.f; for (int w=0;w<8;++w) ss += red[w];
        red[17] = 1.f/ss;
      }
      __syncthreads();
      ab[tid] = f2bf(p * red[17]);
    }
    __syncthreads();
    // sx[u-slice per wave] = a(1x512) @ ehT-rows : D-row0 = result
    {
      f32x4 acX[4];
      #pragma unroll
      for (int i=0;i<4;++i) acX[i] = (f32x4){0.f,0.f,0.f,0.f};
      #pragma unroll
      for (int kt=0;kt<16;++kt){
        short8 afa = (short8){0,0,0,0,0,0,0,0};
        if (bl) afa = *(const short8*)&ab[kt*32 + (lane>>4)*8];
        #pragma unroll
        for (int ut=0;ut<4;++ut){
          short8 bfe = *(const short8*)(ehTg + (size_t)(wave*64 + ut*16 + (lane&15))*TX_ + kt*32 + (lane>>4)*8);
          acX[ut] = __builtin_amdgcn_mfma_f32_16x16x32_bf16(afa, bfe, acX[ut], 0,0,0);
        }
      }
      if (lane < 16){
        #pragma unroll
        for (int ut=0;ut<4;++ut){
          int uu = wave*64 + ut*16 + lane;
          float sv = acX[ut][0];
          sxf[(size_t)g*H_ + uu] = sv;
          sxb[(size_t)g*H_ + uu] = f2bf(sv);
        }
      }
    }
    flagbar(flags1, t+1);

    // ===== phase W: gates for units [16g,16g+16), M=32 batches =====
    STAGE32x512(sxb);
    __syncthreads();
    {
      int ar = mt*16 + (lane&15), ak = (lane>>4)*8;
      if (wave < 6){
        f32x4 acc = (f32x4){0.f,0.f,0.f,0.f};
        #pragma unroll
        for (int ks=0;ks<16;++ks)
          acc = __builtin_amdgcn_mfma_f32_16x16x32_bf16(*(const short8*)&stgl[ar][ks*32+ak], fS[ks], acc, 0,0,0);
        int dr = mt*16 + ((lane>>4)<<2), dc = nt*16 + (lane&15);
        #pragma unroll
        for (int r=0;r<4;++r) gS[dr+r][dc] = acc[r];
      }
      __syncthreads();
      STAGE32x512(hdd + (size_t)par*B_*H_);
      __syncthreads();
      if (wave < 6){
        f32x4 acc = (f32x4){0.f,0.f,0.f,0.f};
        #pragma unroll
        for (int ks=0;ks<16;++ks)
          acc = __builtin_amdgcn_mfma_f32_16x16x32_bf16(*(const short8*)&stgl[ar][ks*32+ak], fH[ks], acc, 0,0,0);
        int dr = mt*16 + ((lane>>4)<<2), dc = nt*16 + (lane&15);
        #pragma unroll
        for (int r=0;r<4;++r) gH[dr+r][dc] = acc[r];
      }
    }
    __syncthreads();
    // pointwise: i_n gets gS (sx part) UNSCALED; only gH_n (+bhh_n) is r-scaled
    {
      size_t gyb = ((size_t)pb*TY_ + t)*G3_;
      float iR = bfu(Gy[gyb+u]), iZ = bfu(Gy[gyb+H_+u]), iN = bfu(Gy[gyb+2*H_+u]);
      float r = sigm(iR + gS[pb][pu]    + gH[pb][pu]    + bhR);
      float z = sigm(iZ + gS[pb][16+pu] + gH[pb][16+pu] + bhZ);
      float n = tanh_f(iN + gS[pb][32+pu] + r*(gH[pb][32+pu] + bhN));
      hloc = (1.f-z)*n + z*hloc;
      hdd[(size_t)((t+1)&1)*B_*H_ + pb*H_ + u] = f2bf(hloc);
      float sxv = sxf[(size_t)pb*H_ + u];
      Xfc[((size_t)pb*TY_ + t)*H_ + u] = f2bf(hloc + sxv);
    }
    flagbar(flags2, t+1);
  }
}

extern "C" void kernel_launch(void* const* d_in, const int* in_sizes, int n_in,
                              void* d_out, int out_size, void* d_ws, size_t ws_size,
                              hipStream_t stream) {
  const int*   x     = (const int*)d_in[0];
  const int*   y     = (const int*)d_in[1];
  const float* emb   = (const float*)d_in[2];
  const float* eWih  = (const float*)d_in[3];
  const float* eWhh  = (const float*)d_in[4];
  const float* eBih  = (const float*)d_in[5];
  const float* eBhh  = (const float*)d_in[6];
  const float* dWih  = (const float*)d_in[7];
  const float* dWhh  = (const float*)d_in[8];
  const float* dBih  = (const float*)d_in[9];
  const float* dBhh  = (const float*)d_in[10];
  const float* hinit = (const float*)d_in[11];
  const float* fcW   = (const float*)d_in[12];
  const float* fcB   = (const float*)d_in[13];
  float* out = (float*)d_out;
  (void)in_sizes; (void)n_in; (void)out_size; (void)ws_size;

  char* p = (char*)d_ws;
  auto take = [&](size_t bytes)->char*{ char* r = p; p += (bytes + 255) & ~(size_t)255; return r; };
  u16* Wfc_bf   = (u16*)take((size_t)V_*H_*2);        // 32.8 MB
  u16* ex_bf    = (u16*)take((size_t)B_*TX_*E_*2);    //  8.4 MB
  u16* eWih_bf  = (u16*)take((size_t)G3_*E_*2);
  u16* Gx_bf    = (u16*)take((size_t)B_*TX_*G3_*2);   // 50.3 MB (ehT aliases here after enc)
  u16* eh_bf    = (u16*)take((size_t)B_*TX_*H_*2);    // 33.6 MB
  u16* embY_bf  = (u16*)take((size_t)4096*E_*2);
  u16* dWihE_bf = (u16*)take((size_t)G3_*E_*2);
  u16* Gy_bf    = (u16*)take((size_t)4096*G3_*2);     // 12.6 MB
  u16* Xfc_bf   = (u16*)take((size_t)4096*H_*2);
  u16* eWhh_bf  = (u16*)take((size_t)G3_*H_*2);
  u16* dWhh_bf  = (u16*)take((size_t)G3_*H_*2);
  u16* dWihS_bf = (u16*)take((size_t)G3_*H_*2);
  u16* hgd      = (u16*)take((size_t)2*B_*H_*2);
  u16* hdd      = (u16*)take((size_t)2*B_*H_*2);
  float* sxf    = (float*)take((size_t)B_*H_*4);
  u16* sxb      = (u16*)take((size_t)B_*H_*2);
  int* flagsE   = (int*)take(256);
  int* flags1   = (int*)take(256);
  int* flags2   = (int*)take(256);
  u16* ehT_bf   = Gx_bf;   // alias: Gx dead after enc; ehT built after enc

  hipMemsetAsync(flagsE, 0, 256, stream);
  hipMemsetAsync(flags1, 0, 256, stream);
  hipMemsetAsync(flags2, 0, 256, stream);
  hipMemsetAsync(hgd, 0, (size_t)2*B_*H_*2, stream);
  hipMemsetAsync(hdd, 0, (size_t)2*B_*H_*2, stream);

  // weight conversions
  cvt_rows<<<dim3(V_),  dim3(256), 0, stream>>>(fcW,  H_, 0, Wfc_bf,   H_);
  cvt_rows<<<dim3(G3_), dim3(256), 0, stream>>>(eWih, E_, 0, eWih_bf,  E_);
  cvt_rows<<<dim3(G3_), dim3(256), 0, stream>>>(dWih, E_+H_, 0, dWihE_bf, E_);
  cvt_rows<<<dim3(G3_), dim3(256), 0, stream>>>(eWhh, H_, 0, eWhh_bf,  H_);
  cvt_rows<<<dim3(G3_), dim3(256), 0, stream>>>(dWhh, H_, 0, dWhh_bf,  H_);
  cvt_rows<<<dim3(G3_), dim3(256), 0, stream>>>(dWih, E_+H_, E_, dWihS_bf, H_);

  // embedding gathers
  gather_embed<<<dim3(B_*TX_), dim3(E_), 0, stream>>>(emb, x, ex_bf, TX_, TX_);
  gather_embed<<<dim3(B_*TY_), dim3(E_), 0, stream>>>(emb, y, embY_bf, TY_, 128);

  // input-gate precomputes
  gemm_bf16<<<dim3(B_*TX_/128, G3_/128), dim3(256), 0, stream>>>(
      ex_bf, E_, eWih_bf, E_, Gx_bf, G3_, eBih, B_*TX_, E_, 1);
  gemm_bf16<<<dim3(32, G3_/128), dim3(256), 0, stream>>>(
      embY_bf, E_, dWihE_bf, E_, Gy_bf, G3_, dBih, B_*TY_, E_, 1);

  // encoder scan (Gx consumed here; its buffer is reused as ehT below)
  enc_v2<<<dim3(32), dim3(512), 0, stream>>>(Gx_bf, eWhh_bf, eBhh, eh_bf, hgd, flagsE);

  // ehT for the decoder PV step
  transpose_eh<<<dim3(B_, TX_/64, H_/64), dim3(256), 0, stream>>>(eh_bf, ehT_bf);

  // decoder scan
  dec_v2<<<dim3(32), dim3(512), 0, stream>>>(eh_bf, ehT_bf, Gy_bf, dWihS_bf, dWhh_bf,
                                             dBhh, hinit, sxf, sxb, hdd, Xfc_bf,
                                             flags1, flags2);

  // final FC: (4064x512) @ (32000x512)^T + fc_b -> f32 out
  gemm_bf16<<<dim3(32, V_/128), dim3(256), 0, stream>>>(
      Xfc_bf, H_, Wfc_bf, H_, out, V_, fcB, B_*TY_, H_, 0);
}

// Round 8
// 7819.180 us; speedup vs baseline: 9.1553x; 1.0881x over previous
//
#include <hip/hip_runtime.h>
#include <hip/hip_bf16.h>

// Seq2Seq GRU+attention, MI355X. Round 8: fence-free cross-block sync.
// All cross-block mutable data (h, sx) moves via sc0+sc1 L2-bypass loads/stores
// (coherent at L3); barriers are relaxed-atomic flags only -> NO buffer_inv /
// wbl2 in the steady loop -> eh/ehT/Gy/weights stay L2-resident across steps.

#define B_  32
#define TX_ 512
#define TY_ 127
#define E_  256
#define H_  512
#define G3_ 1536
#define V_  32000

typedef unsigned short u16;
typedef short short8 __attribute__((ext_vector_type(8)));
typedef float f32x4 __attribute__((ext_vector_type(4)));
typedef unsigned int u32x4 __attribute__((ext_vector_type(4)));

__device__ __forceinline__ float bfu(u16 h){ union{unsigned u; float f;} x; x.u=((unsigned)h)<<16; return x.f; }
__device__ __forceinline__ u16 f2bf(float f){ union{float f; unsigned u;} v; v.f=f; unsigned r=v.u+0x7fffu+((v.u>>16)&1u); return (u16)(r>>16); }
__device__ __forceinline__ float sigm(float x){ return 1.f/(1.f+__expf(-x)); }
__device__ __forceinline__ float tanh_f(float x){ return 1.f - 2.f/(__expf(2.f*x)+1.f); }

// ---- L2-bypass (coherent-point) accessors ----
__device__ __forceinline__ u32x4 ld16_c(const void* p){
  u32x4 r;
  asm volatile("global_load_dwordx4 %0, %1, off sc0 sc1\n\ts_waitcnt vmcnt(0)"
               : "=v"(r) : "v"(p) : "memory");
  return r;
}
__device__ __forceinline__ void st_u16_c(void* p, unsigned v){
  asm volatile("global_store_short %0, %1, off sc0 sc1" :: "v"(p), "v"(v) : "memory");
}

// fence-free barrier over 32 blocks
__device__ __forceinline__ void bar_arrive(int* flags, int tgt){
  __syncthreads();   // drains each wave's vmem (incl. sc1 stores) before s_barrier
  if (threadIdx.x == 0)
    __hip_atomic_store(&flags[blockIdx.x], tgt, __ATOMIC_RELAXED, __HIP_MEMORY_SCOPE_AGENT);
}
__device__ __forceinline__ void bar_wait(int* flags, int tgt){
  if (threadIdx.x < 32){
    int n = 0;
    while (__hip_atomic_load(&flags[threadIdx.x], __ATOMIC_RELAXED, __HIP_MEMORY_SCOPE_AGENT) < tgt){
      __builtin_amdgcn_s_sleep(1);
      if (++n > (1<<22)) break;   // bounded: bug -> wrong output, not hang
    }
  }
  __syncthreads();
  asm volatile("" ::: "memory");  // block compiler reordering; HW is in-order
}

// stage [32][512] bf16 (sc1-written) global -> stgl LDS via bypass loads
__device__ __forceinline__ void stage4_c(u16 (*stgl)[520], const u16* src, int tid){
  const u16* b0 = src + (size_t)(tid>>6)*H_ + (tid&63)*8;
  const u16* b1 = b0 + (size_t)8*H_;
  const u16* b2 = b0 + (size_t)16*H_;
  const u16* b3 = b0 + (size_t)24*H_;
  u32x4 q0,q1,q2,q3;
  asm volatile(
    "global_load_dwordx4 %0, %4, off sc0 sc1\n\t"
    "global_load_dwordx4 %1, %5, off sc0 sc1\n\t"
    "global_load_dwordx4 %2, %6, off sc0 sc1\n\t"
    "global_load_dwordx4 %3, %7, off sc0 sc1\n\t"
    "s_waitcnt vmcnt(0)"
    : "=&v"(q0),"=&v"(q1),"=&v"(q2),"=&v"(q3)
    : "v"(b0),"v"(b1),"v"(b2),"v"(b3) : "memory");
  int r = tid>>6, c = (tid&63)*8;
  *(u32x4*)&stgl[r][c]    = q0;
  *(u32x4*)&stgl[r+8][c]  = q1;
  *(u32x4*)&stgl[r+16][c] = q2;
  *(u32x4*)&stgl[r+24][c] = q3;
}

// ---------- f32 -> bf16 row converter ----------
__global__ void cvt_rows(const float* __restrict__ src, int sld, int soff,
                         u16* __restrict__ dst, int cols){
  int r = blockIdx.x;
  const float* s = src + (size_t)r*sld + soff;
  u16* d = dst + (size_t)r*cols;
  for (int c = threadIdx.x; c < cols; c += blockDim.x) d[c] = f2bf(s[c]);
}

// ---------- embedding gather -> bf16 rows ----------
__global__ void gather_embed(const float* __restrict__ emb, const int* __restrict__ idx,
                             u16* __restrict__ dst, int rows_per_b, int ld){
  int m = blockIdx.x;
  int bb = m / rows_per_b, tt = m - bb*rows_per_b;
  int id = idx[bb*ld + tt];
  dst[(size_t)m*E_ + threadIdx.x] = f2bf(emb[(size_t)id*E_ + threadIdx.x]);
}

// ---------- bf16 MFMA GEMM: C[M,N] = A[M,K] @ B[N,K]^T + bias ----------
__global__ __launch_bounds__(256) void gemm_bf16(
    const u16* __restrict__ A, int lda, const u16* __restrict__ Bm, int ldb,
    void* __restrict__ Cout, int ldc, const float* __restrict__ bias,
    int M, int K, int out_bf16)
{
  int wave = threadIdx.x >> 6, lane = threadIdx.x & 63;
  int m0 = blockIdx.x*128 + (wave>>1)*64;
  int n0 = blockIdx.y*128 + (wave&1)*64;
  int lr = lane & 15, lk = (lane>>4)*8;
  f32x4 acc[4][4];
  #pragma unroll
  for (int i=0;i<4;++i)
    #pragma unroll
    for (int j=0;j<4;++j) acc[i][j] = (f32x4){0.f,0.f,0.f,0.f};
  for (int k0=0; k0<K; k0+=32){
    short8 af[4], bfv[4];
    #pragma unroll
    for (int i=0;i<4;++i){
      int row = m0 + i*16 + lr; if (row > M-1) row = M-1;
      af[i] = *(const short8*)(A + (size_t)row*lda + k0 + lk);
    }
    #pragma unroll
    for (int j=0;j<4;++j){
      int col = n0 + j*16 + lr;
      bfv[j] = *(const short8*)(Bm + (size_t)col*ldb + k0 + lk);
    }
    #pragma unroll
    for (int i=0;i<4;++i)
      #pragma unroll
      for (int j=0;j<4;++j)
        acc[i][j] = __builtin_amdgcn_mfma_f32_16x16x32_bf16(af[i], bfv[j], acc[i][j], 0,0,0);
  }
  int rbase = (lane>>4)*4;
  #pragma unroll
  for (int i=0;i<4;++i)
    #pragma unroll
    for (int r=0;r<4;++r){
      int row = m0 + i*16 + rbase + r;
      if (row < M){
        #pragma unroll
        for (int j=0;j<4;++j){
          int col = n0 + j*16 + lr;
          float v = acc[i][j][r] + bias[col];
          if (out_bf16) ((u16*)Cout)[(size_t)row*ldc + col] = f2bf(v);
          else          ((float*)Cout)[(size_t)row*ldc + col] = v;
        }
      }
    }
}

// ---------- eh[b][t][u] -> ehT[b][u][t] ----------
__global__ __launch_bounds__(256) void transpose_eh(const u16* __restrict__ eh, u16* __restrict__ ehT){
  int b = blockIdx.x, tb = blockIdx.y, ub = blockIdx.z;
  __shared__ u16 tile[64][65];
  int c = threadIdx.x & 63, r0 = threadIdx.x >> 6;
  const u16* src = eh + (size_t)b*TX_*H_;
  #pragma unroll
  for (int r=r0; r<64; r+=4) tile[r][c] = src[(size_t)(tb*64+r)*H_ + ub*64 + c];
  __syncthreads();
  u16* dst = ehT + (size_t)b*H_*TX_;
  #pragma unroll
  for (int r=r0; r<64; r+=4) dst[(size_t)(ub*64+r)*TX_ + tb*64 + c] = tile[c][r];
}

// ---------- encoder: 32 blocks x 512 thr; block g owns units [16g,16g+16) ----------
__global__ __launch_bounds__(512,2) void enc_v2(
    const u16* __restrict__ Gx, const u16* __restrict__ Whh_bf,
    const float* __restrict__ bhh, u16* __restrict__ eh,
    u16* __restrict__ hgd, int* flags)
{
  __shared__ __align__(16) u16 stgl[32][520];
  __shared__ __align__(16) float gH[32][52];
  int tid = threadIdx.x, g = blockIdx.x;
  int wave = tid>>6, lane = tid&63;
  int pb = tid>>4, pu = tid&15, u = g*16 + pu;

  short8 fH[16];
  int mt = wave/3, nt = wave%3;
  if (wave < 6){
    int row = nt*H_ + g*16 + (lane&15);
    int kb = (lane>>4)*8;
    #pragma unroll
    for (int ks=0;ks<16;++ks)
      fH[ks] = *(const short8*)(Whh_bf + (size_t)row*H_ + ks*32 + kb);
  }
  float bhR = bhh[u], bhZ = bhh[u+H_], bhN = bhh[u+2*H_];
  float hloc = 0.f;

  for (int t=0;t<TX_;++t){
    // issue pointwise inputs early (cached loads; overlap with staging)
    size_t gxb = ((size_t)pb*TX_ + t)*G3_;
    float iR = bfu(Gx[gxb+u]), iZ = bfu(Gx[gxb+H_+u]), iN = bfu(Gx[gxb+2*H_+u]);
    stage4_c(stgl, hgd + (size_t)(t&1)*B_*H_, tid);
    __syncthreads();
    if (wave < 6){
      f32x4 acc = (f32x4){0.f,0.f,0.f,0.f};
      int ar = mt*16 + (lane&15), ak = (lane>>4)*8;
      #pragma unroll
      for (int ks=0;ks<16;++ks)
        acc = __builtin_amdgcn_mfma_f32_16x16x32_bf16(*(const short8*)&stgl[ar][ks*32+ak], fH[ks], acc, 0,0,0);
      int dr = mt*16 + ((lane>>4)<<2), dc = nt*16 + (lane&15);
      #pragma unroll
      for (int r=0;r<4;++r) gH[dr+r][dc] = acc[r];
    }
    __syncthreads();
    float r = sigm(iR + gH[pb][pu]    + bhR);
    float z = sigm(iZ + gH[pb][16+pu] + bhZ);
    float n = tanh_f(iN + r*(gH[pb][32+pu] + bhN));
    hloc = (1.f-z)*n + z*hloc;
    u16 hb = f2bf(hloc);
    st_u16_c(&hgd[(size_t)((t+1)&1)*B_*H_ + (size_t)pb*H_ + u], (unsigned)hb);
    eh[((size_t)pb*TX_ + t)*H_ + u] = hb;   // normal store; consumed by later kernels
    bar_arrive(flags, t+1);
    bar_wait(flags, t+1);
  }
}

// ---------- decoder: 32 blocks x 512 thr ----------
__global__ __launch_bounds__(512,2) void dec_v2(
    const u16* __restrict__ eh, const u16* __restrict__ ehT,
    const u16* __restrict__ Gy,
    const u16* __restrict__ WihS_bf, const u16* __restrict__ Whh_bf,
    const float* __restrict__ dbhh, const float* __restrict__ hinit,
    u16* __restrict__ sxb, u16* __restrict__ hdd, u16* __restrict__ Xfc,
    int* flags1, int* flags2)
{
  __shared__ __align__(16) u16 stgl[32][520];
  __shared__ __align__(16) float gS[32][52], gH[32][52];
  __shared__ __align__(16) u16 oxb[520], ab[520];
  __shared__ __align__(16) float sc[512];
  __shared__ float red[32];
  int tid = threadIdx.x, g = blockIdx.x;
  int wave = tid>>6, lane = tid&63;
  int pb = tid>>4, pu = tid&15, u = g*16 + pu;

  short8 fS[16], fH[16];
  int mt = wave/3, nt = wave%3;
  if (wave < 6){
    int row = nt*H_ + g*16 + (lane&15);
    int kb = (lane>>4)*8;
    #pragma unroll
    for (int ks=0;ks<16;++ks){
      fS[ks] = *(const short8*)(WihS_bf + (size_t)row*H_ + ks*32 + kb);
      fH[ks] = *(const short8*)(Whh_bf  + (size_t)row*H_ + ks*32 + kb);
    }
  }
  float bhR = dbhh[u], bhZ = dbhh[u+H_], bhN = dbhh[u+2*H_];
  float hloc = 0.f;
  const u16* ehg  = eh  + (size_t)g*TX_*H_;
  const u16* ehTg = ehT + (size_t)g*H_*TX_;
  bool bl = (lane&15) == 0;

  for (int t=0;t<TY_;++t){
    int par = t&1;
    // ===== phase A: attention for batch g =====
    if (t == 0){
      oxb[tid] = f2bf(hinit[tid]);
    } else if (tid < 64){
      u32x4 q = ld16_c(hdd + (size_t)par*B_*H_ + (size_t)g*H_ + tid*8);
      *(u32x4*)&oxb[tid*8] = q;
    }
    __syncthreads();
    { // scores: D-col0 = eh_rows @ ox
      f32x4 acS[4];
      #pragma unroll
      for (int i=0;i<4;++i) acS[i] = (f32x4){0.f,0.f,0.f,0.f};
      #pragma unroll
      for (int kt=0;kt<16;++kt){
        short8 bf = (short8){0,0,0,0,0,0,0,0};
        if (bl) bf = *(const short8*)&oxb[kt*32 + (lane>>4)*8];
        #pragma unroll
        for (int m2=0;m2<4;++m2){
          short8 af = *(const short8*)(ehg + (size_t)(wave*64 + m2*16 + (lane&15))*H_ + kt*32 + (lane>>4)*8);
          acS[m2] = __builtin_amdgcn_mfma_f32_16x16x32_bf16(af, bf, acS[m2], 0,0,0);
        }
      }
      if (bl){
        #pragma unroll
        for (int m2=0;m2<4;++m2)
          #pragma unroll
          for (int r=0;r<4;++r)
            sc[wave*64 + m2*16 + (lane>>4)*4 + r] = acS[m2][r];
      }
    }
    __syncthreads();
    { // softmax over 512 scores
      float v = sc[tid];
      float m = v;
      #pragma unroll
      for (int o=32;o>0;o>>=1) m = fmaxf(m, __shfl_xor(m, o));
      if (lane==0) red[wave] = m;
      __syncthreads();
      if (tid==0){
        float mm = red[0];
        for (int w=1;w<8;++w) mm = fmaxf(mm, red[w]);
        red[16] = mm;
      }
      __syncthreads();
      float M = red[16];
      float p = __expf(v - M);
      float s = p;
      #pragma unroll
      for (int o=32;o>0;o>>=1) s += __shfl_xor(s, o);
      if (lane==0) red[wave] = s;
      __syncthreads();
      if (tid==0){
        float ss = 0.f; for (int w=0;w<8;++w) ss += red[w];
        red[17] = 1.f/ss;
      }
      __syncthreads();
      ab[tid] = f2bf(p * red[17]);
    }
    __syncthreads();
    { // sx = a(1x512) @ ehT-rows : D-row0
      f32x4 acX[4];
      #pragma unroll
      for (int i=0;i<4;++i) acX[i] = (f32x4){0.f,0.f,0.f,0.f};
      #pragma unroll
      for (int kt=0;kt<16;++kt){
        short8 afa = (short8){0,0,0,0,0,0,0,0};
        if (bl) afa = *(const short8*)&ab[kt*32 + (lane>>4)*8];
        #pragma unroll
        for (int ut=0;ut<4;++ut){
          short8 bfe = *(const short8*)(ehTg + (size_t)(wave*64 + ut*16 + (lane&15))*TX_ + kt*32 + (lane>>4)*8);
          acX[ut] = __builtin_amdgcn_mfma_f32_16x16x32_bf16(afa, bfe, acX[ut], 0,0,0);
        }
      }
      if (lane < 16){
        #pragma unroll
        for (int ut=0;ut<4;++ut){
          int uu = wave*64 + ut*16 + lane;
          st_u16_c(&sxb[(size_t)g*H_ + uu], (unsigned)f2bf(acX[ut][0]));
        }
      }
    }
    bar_arrive(flags1, t+1);
    bar_wait(flags1, t+1);

    // ===== phase W: gates for units [16g,16g+16), M=32 batches =====
    size_t gyb = ((size_t)pb*TY_ + t)*G3_;   // cached loads, issued early
    float iR = bfu(Gy[gyb+u]), iZ = bfu(Gy[gyb+H_+u]), iN = bfu(Gy[gyb+2*H_+u]);
    stage4_c(stgl, sxb, tid);
    __syncthreads();
    float sxv = bfu(stgl[pb][u]);   // sx for (batch pb, unit u), before overwrite
    int ar = mt*16 + (lane&15), ak = (lane>>4)*8;
    if (wave < 6){
      f32x4 acc = (f32x4){0.f,0.f,0.f,0.f};
      #pragma unroll
      for (int ks=0;ks<16;++ks)
        acc = __builtin_amdgcn_mfma_f32_16x16x32_bf16(*(const short8*)&stgl[ar][ks*32+ak], fS[ks], acc, 0,0,0);
      int dr = mt*16 + ((lane>>4)<<2), dc = nt*16 + (lane&15);
      #pragma unroll
      for (int r=0;r<4;++r) gS[dr+r][dc] = acc[r];
    }
    __syncthreads();
    stage4_c(stgl, hdd + (size_t)par*B_*H_, tid);
    __syncthreads();
    if (wave < 6){
      f32x4 acc = (f32x4){0.f,0.f,0.f,0.f};
      #pragma unroll
      for (int ks=0;ks<16;++ks)
        acc = __builtin_amdgcn_mfma_f32_16x16x32_bf16(*(const short8*)&stgl[ar][ks*32+ak], fH[ks], acc, 0,0,0);
      int dr = mt*16 + ((lane>>4)<<2), dc = nt*16 + (lane&15);
      #pragma unroll
      for (int r=0;r<4;++r) gH[dr+r][dc] = acc[r];
    }
    __syncthreads();
    { // pointwise: i_n gets gS (sx part) UNSCALED; only gH_n (+bhh_n) r-scaled
      float r = sigm(iR + gS[pb][pu]    + gH[pb][pu]    + bhR);
      float z = sigm(iZ + gS[pb][16+pu] + gH[pb][16+pu] + bhZ);
      float n = tanh_f(iN + gS[pb][32+pu] + r*(gH[pb][32+pu] + bhN));
      hloc = (1.f-z)*n + z*hloc;
      st_u16_c(&hdd[(size_t)((t+1)&1)*B_*H_ + (size_t)pb*H_ + u], (unsigned)f2bf(hloc));
      Xfc[((size_t)pb*TY_ + t)*H_ + u] = f2bf(hloc + sxv);   // normal store
    }
    bar_arrive(flags2, t+1);
    bar_wait(flags2, t+1);
  }
}

extern "C" void kernel_launch(void* const* d_in, const int* in_sizes, int n_in,
                              void* d_out, int out_size, void* d_ws, size_t ws_size,
                              hipStream_t stream) {
  const int*   x     = (const int*)d_in[0];
  const int*   y     = (const int*)d_in[1];
  const float* emb   = (const float*)d_in[2];
  const float* eWih  = (const float*)d_in[3];
  const float* eWhh  = (const float*)d_in[4];
  const float* eBih  = (const float*)d_in[5];
  const float* eBhh  = (const float*)d_in[6];
  const float* dWih  = (const float*)d_in[7];
  const float* dWhh  = (const float*)d_in[8];
  const float* dBih  = (const float*)d_in[9];
  const float* dBhh  = (const float*)d_in[10];
  const float* hinit = (const float*)d_in[11];
  const float* fcW   = (const float*)d_in[12];
  const float* fcB   = (const float*)d_in[13];
  float* out = (float*)d_out;
  (void)in_sizes; (void)n_in; (void)out_size; (void)ws_size;

  char* p = (char*)d_ws;
  auto take = [&](size_t bytes)->char*{ char* r = p; p += (bytes + 255) & ~(size_t)255; return r; };
  u16* Wfc_bf   = (u16*)take((size_t)V_*H_*2);
  u16* ex_bf    = (u16*)take((size_t)B_*TX_*E_*2);
  u16* eWih_bf  = (u16*)take((size_t)G3_*E_*2);
  u16* Gx_bf    = (u16*)take((size_t)B_*TX_*G3_*2);   // ehT aliases here after enc
  u16* eh_bf    = (u16*)take((size_t)B_*TX_*H_*2);
  u16* embY_bf  = (u16*)take((size_t)4096*E_*2);
  u16* dWihE_bf = (u16*)take((size_t)G3_*E_*2);
  u16* Gy_bf    = (u16*)take((size_t)4096*G3_*2);
  u16* Xfc_bf   = (u16*)take((size_t)4096*H_*2);
  u16* eWhh_bf  = (u16*)take((size_t)G3_*H_*2);
  u16* dWhh_bf  = (u16*)take((size_t)G3_*H_*2);
  u16* dWihS_bf = (u16*)take((size_t)G3_*H_*2);
  u16* hgd      = (u16*)take((size_t)2*B_*H_*2);
  u16* hdd      = (u16*)take((size_t)2*B_*H_*2);
  u16* sxb      = (u16*)take((size_t)B_*H_*2);
  int* flagsE   = (int*)take(256);
  int* flags1   = (int*)take(256);
  int* flags2   = (int*)take(256);
  u16* ehT_bf   = Gx_bf;

  hipMemsetAsync(flagsE, 0, 256, stream);
  hipMemsetAsync(flags1, 0, 256, stream);
  hipMemsetAsync(flags2, 0, 256, stream);
  hipMemsetAsync(hgd, 0, (size_t)2*B_*H_*2, stream);
  hipMemsetAsync(hdd, 0, (size_t)2*B_*H_*2, stream);

  cvt_rows<<<dim3(V_),  dim3(256), 0, stream>>>(fcW,  H_, 0, Wfc_bf,   H_);
  cvt_rows<<<dim3(G3_), dim3(256), 0, stream>>>(eWih, E_, 0, eWih_bf,  E_);
  cvt_rows<<<dim3(G3_), dim3(256), 0, stream>>>(dWih, E_+H_, 0, dWihE_bf, E_);
  cvt_rows<<<dim3(G3_), dim3(256), 0, stream>>>(eWhh, H_, 0, eWhh_bf,  H_);
  cvt_rows<<<dim3(G3_), dim3(256), 0, stream>>>(dWhh, H_, 0, dWhh_bf,  H_);
  cvt_rows<<<dim3(G3_), dim3(256), 0, stream>>>(dWih, E_+H_, E_, dWihS_bf, H_);

  gather_embed<<<dim3(B_*TX_), dim3(E_), 0, stream>>>(emb, x, ex_bf, TX_, TX_);
  gather_embed<<<dim3(B_*TY_), dim3(E_), 0, stream>>>(emb, y, embY_bf, TY_, 128);

  gemm_bf16<<<dim3(B_*TX_/128, G3_/128), dim3(256), 0, stream>>>(
      ex_bf, E_, eWih_bf, E_, Gx_bf, G3_, eBih, B_*TX_, E_, 1);
  gemm_bf16<<<dim3(32, G3_/128), dim3(256), 0, stream>>>(
      embY_bf, E_, dWihE_bf, E_, Gy_bf, G3_, dBih, B_*TY_, E_, 1);

  enc_v2<<<dim3(32), dim3(512), 0, stream>>>(Gx_bf, eWhh_bf, eBhh, eh_bf, hgd, flagsE);

  transpose_eh<<<dim3(B_, TX_/64, H_/64), dim3(256), 0, stream>>>(eh_bf, ehT_bf);

  dec_v2<<<dim3(32), dim3(512), 0, stream>>>(eh_bf, ehT_bf, Gy_bf, dWihS_bf, dWhh_bf,
                                             dBhh, hinit, sxb, hdd, Xfc_bf,
                                             flags1, flags2);

  gemm_bf16<<<dim3(32, V_/128), dim3(256), 0, stream>>>(
      Xfc_bf, H_, Wfc_bf, H_, out, V_, fcB, B_*TY_, H_, 0);
}

// Round 10
// 3644.447 us; speedup vs baseline: 19.6426x; 2.1455x over previous
//
#include <hip/hip_runtime.h>
#include <hip/hip_bf16.h>

// Seq2Seq GRU+attention, MI355X. Round 10: r9 + W-coverage fix (32 W-blocks
// x 16 units = 512 = H; r9 had 16 -> half the units never computed).
// dec: 128 A-blocks hold eh quarters in LDS (146KB, swizzled, loaded once);
// 4-way online-softmax stats exchange; 32 W-blocks = r8 gate phase.
// Sync: relaxed flags + sc0sc1 bypass data (r8-proven).

#define B_  32
#define TX_ 512
#define TY_ 127
#define E_  256
#define H_  512
#define G3_ 1536
#define V_  32000
#define NA_ 128
#define NW_ 32

typedef unsigned short u16;
typedef short short8 __attribute__((ext_vector_type(8)));
typedef float f32x4 __attribute__((ext_vector_type(4)));
typedef float f32x2 __attribute__((ext_vector_type(2)));
typedef unsigned int u32x4 __attribute__((ext_vector_type(4)));

__device__ __forceinline__ float bfu(u16 h){ union{unsigned u; float f;} x; x.u=((unsigned)h)<<16; return x.f; }
__device__ __forceinline__ u16 f2bf(float f){ union{float f; unsigned u;} v; v.f=f; unsigned r=v.u+0x7fffu+((v.u>>16)&1u); return (u16)(r>>16); }
__device__ __forceinline__ float sigm(float x){ return 1.f/(1.f+__expf(-x)); }
__device__ __forceinline__ float tanh_f(float x){ return 1.f - 2.f/(__expf(2.f*x)+1.f); }

// ---- L2-bypass (coherent-point) accessors ----
__device__ __forceinline__ u32x4 ld16_c(const void* p){
  u32x4 r;
  asm volatile("global_load_dwordx4 %0, %1, off sc0 sc1\n\ts_waitcnt vmcnt(0)"
               : "=v"(r) : "v"(p) : "memory");
  return r;
}
__device__ __forceinline__ f32x2 ld8_c(const void* p){
  f32x2 r;
  asm volatile("global_load_dwordx2 %0, %1, off sc0 sc1\n\ts_waitcnt vmcnt(0)"
               : "=v"(r) : "v"(p) : "memory");
  return r;
}
__device__ __forceinline__ float ld4f_c(const void* p){
  float r;
  asm volatile("global_load_dword %0, %1, off sc0 sc1\n\ts_waitcnt vmcnt(0)"
               : "=v"(r) : "v"(p) : "memory");
  return r;
}
__device__ __forceinline__ void st_u16_c(void* p, unsigned v){
  asm volatile("global_store_short %0, %1, off sc0 sc1" :: "v"(p), "v"(v) : "memory");
}
__device__ __forceinline__ void st8_c(void* p, float a, float b){
  f32x2 v; v.x=a; v.y=b;
  asm volatile("global_store_dwordx2 %0, %1, off sc0 sc1" :: "v"(p), "v"(v) : "memory");
}
__device__ __forceinline__ void st4f_c(void* p, float v){
  asm volatile("global_store_dword %0, %1, off sc0 sc1" :: "v"(p), "v"(v) : "memory");
}

__device__ __forceinline__ void spin_rel(int* p, int tgt){
  int n = 0;
  while (__hip_atomic_load(p, __ATOMIC_RELAXED, __HIP_MEMORY_SCOPE_AGENT) < tgt){
    __builtin_amdgcn_s_sleep(1);
    if (++n > (1<<22)) break;   // bounded: bug -> wrong output, not hang
  }
}

// flag barrier over 32 blocks (encoder)
__device__ __forceinline__ void flagbar(int* flags, int target){
  __syncthreads();
  if (threadIdx.x == 0)
    __hip_atomic_store(&flags[blockIdx.x], target, __ATOMIC_RELAXED, __HIP_MEMORY_SCOPE_AGENT);
  if (threadIdx.x < 32) spin_rel(&flags[threadIdx.x], target);
  __syncthreads();
  asm volatile("" ::: "memory");
}

// stage [32][512] bf16 (sc1-written) global -> stgl LDS via bypass loads
__device__ __forceinline__ void stage4_c(u16 (*stgl)[520], const u16* src, int tid){
  const u16* b0 = src + (size_t)(tid>>6)*H_ + (tid&63)*8;
  const u16* b1 = b0 + (size_t)8*H_;
  const u16* b2 = b0 + (size_t)16*H_;
  const u16* b3 = b0 + (size_t)24*H_;
  u32x4 q0,q1,q2,q3;
  asm volatile(
    "global_load_dwordx4 %0, %4, off sc0 sc1\n\t"
    "global_load_dwordx4 %1, %5, off sc0 sc1\n\t"
    "global_load_dwordx4 %2, %6, off sc0 sc1\n\t"
    "global_load_dwordx4 %3, %7, off sc0 sc1\n\t"
    "s_waitcnt vmcnt(0)"
    : "=&v"(q0),"=&v"(q1),"=&v"(q2),"=&v"(q3)
    : "v"(b0),"v"(b1),"v"(b2),"v"(b3) : "memory");
  int r = tid>>6, c = (tid&63)*8;
  *(u32x4*)&stgl[r][c]    = q0;
  *(u32x4*)&stgl[r+8][c]  = q1;
  *(u32x4*)&stgl[r+16][c] = q2;
  *(u32x4*)&stgl[r+24][c] = q3;
}

// ---------- f32 -> bf16 row converter ----------
__global__ void cvt_rows(const float* __restrict__ src, int sld, int soff,
                         u16* __restrict__ dst, int cols){
  int r = blockIdx.x;
  const float* s = src + (size_t)r*sld + soff;
  u16* d = dst + (size_t)r*cols;
  for (int c = threadIdx.x; c < cols; c += blockDim.x) d[c] = f2bf(s[c]);
}

// ---------- embedding gather -> bf16 rows ----------
__global__ void gather_embed(const float* __restrict__ emb, const int* __restrict__ idx,
                             u16* __restrict__ dst, int rows_per_b, int ld){
  int m = blockIdx.x;
  int bb = m / rows_per_b, tt = m - bb*rows_per_b;
  int id = idx[bb*ld + tt];
  dst[(size_t)m*E_ + threadIdx.x] = f2bf(emb[(size_t)id*E_ + threadIdx.x]);
}

// ---------- bf16 MFMA GEMM: C[M,N] = A[M,K] @ B[N,K]^T + bias ----------
__global__ __launch_bounds__(256) void gemm_bf16(
    const u16* __restrict__ A, int lda, const u16* __restrict__ Bm, int ldb,
    void* __restrict__ Cout, int ldc, const float* __restrict__ bias,
    int M, int K, int out_bf16)
{
  int wave = threadIdx.x >> 6, lane = threadIdx.x & 63;
  int m0 = blockIdx.x*128 + (wave>>1)*64;
  int n0 = blockIdx.y*128 + (wave&1)*64;
  int lr = lane & 15, lk = (lane>>4)*8;
  f32x4 acc[4][4];
  #pragma unroll
  for (int i=0;i<4;++i)
    #pragma unroll
    for (int j=0;j<4;++j) acc[i][j] = (f32x4){0.f,0.f,0.f,0.f};
  for (int k0=0; k0<K; k0+=32){
    short8 af[4], bfv[4];
    #pragma unroll
    for (int i=0;i<4;++i){
      int row = m0 + i*16 + lr; if (row > M-1) row = M-1;
      af[i] = *(const short8*)(A + (size_t)row*lda + k0 + lk);
    }
    #pragma unroll
    for (int j=0;j<4;++j){
      int col = n0 + j*16 + lr;
      bfv[j] = *(const short8*)(Bm + (size_t)col*ldb + k0 + lk);
    }
    #pragma unroll
    for (int i=0;i<4;++i)
      #pragma unroll
      for (int j=0;j<4;++j)
        acc[i][j] = __builtin_amdgcn_mfma_f32_16x16x32_bf16(af[i], bfv[j], acc[i][j], 0,0,0);
  }
  int rbase = (lane>>4)*4;
  #pragma unroll
  for (int i=0;i<4;++i)
    #pragma unroll
    for (int r=0;r<4;++r){
      int row = m0 + i*16 + rbase + r;
      if (row < M){
        #pragma unroll
        for (int j=0;j<4;++j){
          int col = n0 + j*16 + lr;
          float v = acc[i][j][r] + bias[col];
          if (out_bf16) ((u16*)Cout)[(size_t)row*ldc + col] = f2bf(v);
          else          ((float*)Cout)[(size_t)row*ldc + col] = v;
        }
      }
    }
}

// ---------- encoder: 32 blocks x 512 thr (r8-proven) ----------
__global__ __launch_bounds__(512,2) void enc_v2(
    const u16* __restrict__ Gx, const u16* __restrict__ Whh_bf,
    const float* __restrict__ bhh, u16* __restrict__ eh,
    u16* __restrict__ hgd, int* flags)
{
  __shared__ __align__(16) u16 stgl[32][520];
  __shared__ __align__(16) float gH[32][52];
  int tid = threadIdx.x, g = blockIdx.x;
  int wave = tid>>6, lane = tid&63;
  int pb = tid>>4, pu = tid&15, u = g*16 + pu;

  short8 fH[16];
  int mt = wave/3, nt = wave%3;
  if (wave < 6){
    int row = nt*H_ + g*16 + (lane&15);
    int kb = (lane>>4)*8;
    #pragma unroll
    for (int ks=0;ks<16;++ks)
      fH[ks] = *(const short8*)(Whh_bf + (size_t)row*H_ + ks*32 + kb);
  }
  float bhR = bhh[u], bhZ = bhh[u+H_], bhN = bhh[u+2*H_];
  float hloc = 0.f;

  for (int t=0;t<TX_;++t){
    size_t gxb = ((size_t)pb*TX_ + t)*G3_;
    float iR = bfu(Gx[gxb+u]), iZ = bfu(Gx[gxb+H_+u]), iN = bfu(Gx[gxb+2*H_+u]);
    stage4_c(stgl, hgd + (size_t)(t&1)*B_*H_, tid);
    __syncthreads();
    if (wave < 6){
      f32x4 acc = (f32x4){0.f,0.f,0.f,0.f};
      int ar = mt*16 + (lane&15), ak = (lane>>4)*8;
      #pragma unroll
      for (int ks=0;ks<16;++ks)
        acc = __builtin_amdgcn_mfma_f32_16x16x32_bf16(*(const short8*)&stgl[ar][ks*32+ak], fH[ks], acc, 0,0,0);
      int dr = mt*16 + ((lane>>4)<<2), dc = nt*16 + (lane&15);
      #pragma unroll
      for (int r=0;r<4;++r) gH[dr+r][dc] = acc[r];
    }
    __syncthreads();
    float r = sigm(iR + gH[pb][pu]    + bhR);
    float z = sigm(iZ + gH[pb][16+pu] + bhZ);
    float n = tanh_f(iN + r*(gH[pb][32+pu] + bhN));
    hloc = (1.f-z)*n + z*hloc;
    u16 hb = f2bf(hloc);
    st_u16_c(&hgd[(size_t)((t+1)&1)*B_*H_ + (size_t)pb*H_ + u], (unsigned)hb);
    eh[((size_t)pb*TX_ + t)*H_ + u] = hb;
    flagbar(flags, t+1);
  }
}

// ---------- decoder: 160 blocks x 512 thr (128 A + 32 W) ----------
__global__ __launch_bounds__(512,2) void dec_v3(
    const u16* __restrict__ eh, const u16* __restrict__ Gy,
    const u16* __restrict__ WihS_bf, const u16* __restrict__ Whh_bf,
    const float* __restrict__ dbhh, const float* __restrict__ hinit,
    u16* __restrict__ sxb, u16* __restrict__ hdd,
    float* __restrict__ part, float* __restrict__ statsg,
    u16* __restrict__ Xfc,
    int* Sf, int* Pf, int* Xf, int* Hf)
{
  struct AS {
    u16   ehq[128][512];   // 128KB, swizzled: col ^= (row&7)<<3
    u16   oxb[512];
    float sc[128];
    float af[128];
    float pt[8][512];      // 16KB PV partials
    float red[16];         // [0..7] max-slots, [8..15] sum-slots
    float st4[8];
  };
  struct WS { u16 stgl[32][520]; float gS[32][52]; float gH[32][52]; };
  __shared__ __align__(16) char smem_[sizeof(AS)];
  int tid = threadIdx.x;
  int wave = tid>>6, lane = tid&63;

  if (blockIdx.x < NA_){
    // ===== role A: attention quarter (batch b, chunk q) =====
    AS& S = *(AS*)smem_;
    int b = blockIdx.x >> 2, q = blockIdx.x & 3;
    { // preload eh quarter, swizzled (once; normal cached loads)
      const u16* ehg = eh + ((size_t)b*TX_ + q*128)*H_;
      int row = tid>>2, c0 = (tid&3)*128;
      #pragma unroll
      for (int j=0;j<16;++j){
        int u0 = c0 + j*8;
        uint4 v = *(const uint4*)(ehg + (size_t)row*H_ + u0);
        *(uint4*)&S.ehq[row][u0 ^ ((row&7)<<3)] = v;
      }
    }
    __syncthreads();
    bool bl = (lane&15) == 0;
    for (int t=0;t<TY_;++t){
      // ---- ox ----
      if (t > 0){
        if (tid < NW_) spin_rel(&Hf[tid], t);
        __syncthreads();
        asm volatile("" ::: "memory");
        if (tid < 64){
          u32x4 qv = ld16_c(hdd + (size_t)b*H_ + tid*8);
          *(u32x4*)&S.oxb[tid*8] = qv;
        }
      } else {
        S.oxb[tid] = f2bf(hinit[tid]);
      }
      __syncthreads();
      // ---- scores: rows [wave*16, wave*16+16) from resident LDS ----
      {
        f32x4 acS = (f32x4){0.f,0.f,0.f,0.f};
        int arow = wave*16 + (lane&15);
        int swz = (arow&7)<<3;
        #pragma unroll
        for (int kt=0;kt<16;++kt){
          short8 bf = (short8){0,0,0,0,0,0,0,0};
          if (bl) bf = *(const short8*)&S.oxb[kt*32 + (lane>>4)*8];
          short8 af_ = *(const short8*)&S.ehq[arow][(kt*32 + (lane>>4)*8) ^ swz];
          acS = __builtin_amdgcn_mfma_f32_16x16x32_bf16(af_, bf, acS, 0,0,0);
        }
        if (bl){
          #pragma unroll
          for (int r=0;r<4;++r) S.sc[wave*16 + (lane>>4)*4 + r] = acS[r];
        }
      }
      __syncthreads();
      // ---- local softmax stats (m_q, l_q) ----
      float mq;
      {
        float v = (tid<128) ? S.sc[tid] : -3e38f;
        #pragma unroll
        for (int o=32;o>0;o>>=1) v = fmaxf(v, __shfl_xor(v, o));
        if (lane==0) S.red[wave] = v;
        __syncthreads();
        mq = fmaxf(S.red[0], S.red[1]);
        float e = 0.f;
        if (tid<128){ e = __expf(S.sc[tid] - mq); S.sc[tid] = e; }
        float s2 = e;
        #pragma unroll
        for (int o=32;o>0;o>>=1) s2 += __shfl_xor(s2, o);
        if (lane==0) S.red[8+wave] = s2;   // separate slots: no race with mq reads
        __syncthreads();
        float lq = S.red[8] + S.red[9];
        if (tid==0) st8_c(&statsg[(size_t)(b*4+q)*2], mq, lq);
      }
      __syncthreads();   // drain stats store
      if (tid==0) __hip_atomic_store(&Sf[b*4+q], t+1, __ATOMIC_RELAXED, __HIP_MEMORY_SCOPE_AGENT);
      // ---- combine 4 sibling stats ----
      if (tid < 4) spin_rel(&Sf[b*4+tid], t+1);
      __syncthreads();
      asm volatile("" ::: "memory");
      if (tid < 4){
        f32x2 r2 = ld8_c(&statsg[(size_t)(b*4+tid)*2]);
        S.st4[tid*2] = r2.x; S.st4[tid*2+1] = r2.y;
      }
      __syncthreads();
      float gmax = fmaxf(fmaxf(S.st4[0],S.st4[2]), fmaxf(S.st4[4],S.st4[6]));
      float gsum = S.st4[1]*__expf(S.st4[0]-gmax) + S.st4[3]*__expf(S.st4[2]-gmax)
                 + S.st4[5]*__expf(S.st4[4]-gmax) + S.st4[7]*__expf(S.st4[6]-gmax);
      float scale = __expf(mq - gmax) / gsum;
      if (tid<128) S.af[tid] = S.sc[tid] * scale;
      __syncthreads();
      // ---- PV partial from resident LDS (thread: 8 u's x 16 t') ----
      int u0 = lane*8, tseg = wave;
      f32x4 aLo = (f32x4){0.f,0.f,0.f,0.f}, aHi = (f32x4){0.f,0.f,0.f,0.f};
      #pragma unroll
      for (int j=0;j<16;++j){
        int tp = tseg*16 + j;
        short8 ev = *(const short8*)&S.ehq[tp][u0 ^ ((tp&7)<<3)];
        float av = S.af[tp];
        aLo[0] = fmaf(bfu((u16)ev[0]), av, aLo[0]);
        aLo[1] = fmaf(bfu((u16)ev[1]), av, aLo[1]);
        aLo[2] = fmaf(bfu((u16)ev[2]), av, aLo[2]);
        aLo[3] = fmaf(bfu((u16)ev[3]), av, aLo[3]);
        aHi[0] = fmaf(bfu((u16)ev[4]), av, aHi[0]);
        aHi[1] = fmaf(bfu((u16)ev[5]), av, aHi[1]);
        aHi[2] = fmaf(bfu((u16)ev[6]), av, aHi[2]);
        aHi[3] = fmaf(bfu((u16)ev[7]), av, aHi[3]);
      }
      *(f32x4*)&S.pt[tseg][u0]   = aLo;
      *(f32x4*)&S.pt[tseg][u0+4] = aHi;
      __syncthreads();
      float sv = 0.f;
      #pragma unroll
      for (int gsg=0; gsg<8; ++gsg) sv += S.pt[gsg][tid];
      if (q != 0){
        st4f_c(&part[(size_t)(b*4+q)*512 + tid], sv);
        __syncthreads();   // drain
        if (tid==0) __hip_atomic_store(&Pf[b*4+q], t+1, __ATOMIC_RELAXED, __HIP_MEMORY_SCOPE_AGENT);
      } else {
        if (tid < 3) spin_rel(&Pf[b*4+1+tid], t+1);
        __syncthreads();
        asm volatile("" ::: "memory");
        sv += ld4f_c(&part[(size_t)(b*4+1)*512 + tid]);
        sv += ld4f_c(&part[(size_t)(b*4+2)*512 + tid]);
        sv += ld4f_c(&part[(size_t)(b*4+3)*512 + tid]);
        st_u16_c(&sxb[(size_t)b*H_ + tid], (unsigned)f2bf(sv));
        __syncthreads();   // drain
        if (tid==0) __hip_atomic_store(&Xf[b], t+1, __ATOMIC_RELAXED, __HIP_MEMORY_SCOPE_AGENT);
      }
    }
  } else {
    // ===== role W: gates for units [16g,16g+16), g in [0,32) -> all 512 units =====
    WS& S = *(WS*)smem_;
    int g = blockIdx.x - NA_;
    int pb = tid>>4, pu = tid&15, u = g*16 + pu;
    short8 fS[16], fH[16];
    int mt = wave/3, nt = wave%3;
    if (wave < 6){
      int row = nt*H_ + g*16 + (lane&15);
      int kb = (lane>>4)*8;
      #pragma unroll
      for (int ks=0;ks<16;++ks){
        fS[ks] = *(const short8*)(WihS_bf + (size_t)row*H_ + ks*32 + kb);
        fH[ks] = *(const short8*)(Whh_bf  + (size_t)row*H_ + ks*32 + kb);
      }
    }
    float bhR = dbhh[u], bhZ = dbhh[u+H_], bhN = dbhh[u+2*H_];
    float hloc = 0.f;

    for (int t=0;t<TY_;++t){
      size_t gyb = ((size_t)pb*TY_ + t)*G3_;   // cached, issued early
      float iR = bfu(Gy[gyb+u]), iZ = bfu(Gy[gyb+H_+u]), iN = bfu(Gy[gyb+2*H_+u]);
      if (tid < 32) spin_rel(&Xf[tid], t+1);
      __syncthreads();
      asm volatile("" ::: "memory");
      stage4_c(S.stgl, sxb, tid);
      __syncthreads();
      float sxv = bfu(S.stgl[pb][u]);
      int ar = mt*16 + (lane&15), ak = (lane>>4)*8;
      if (wave < 6){
        f32x4 acc = (f32x4){0.f,0.f,0.f,0.f};
        #pragma unroll
        for (int ks=0;ks<16;++ks)
          acc = __builtin_amdgcn_mfma_f32_16x16x32_bf16(*(const short8*)&S.stgl[ar][ks*32+ak], fS[ks], acc, 0,0,0);
        int dr = mt*16 + ((lane>>4)<<2), dc = nt*16 + (lane&15);
        #pragma unroll
        for (int r=0;r<4;++r) S.gS[dr+r][dc] = acc[r];
      }
      __syncthreads();
      stage4_c(S.stgl, hdd, tid);
      __syncthreads();
      if (wave < 6){
        f32x4 acc = (f32x4){0.f,0.f,0.f,0.f};
        #pragma unroll
        for (int ks=0;ks<16;++ks)
          acc = __builtin_amdgcn_mfma_f32_16x16x32_bf16(*(const short8*)&S.stgl[ar][ks*32+ak], fH[ks], acc, 0,0,0);
        int dr = mt*16 + ((lane>>4)<<2), dc = nt*16 + (lane&15);
        #pragma unroll
        for (int r=0;r<4;++r) S.gH[dr+r][dc] = acc[r];
      }
      __syncthreads();
      { // pointwise: i_n gets gS (sx part) UNSCALED; only gH_n (+bhh_n) r-scaled
        float r = sigm(iR + S.gS[pb][pu]    + S.gH[pb][pu]    + bhR);
        float z = sigm(iZ + S.gS[pb][16+pu] + S.gH[pb][16+pu] + bhZ);
        float n = tanh_f(iN + S.gS[pb][32+pu] + r*(S.gH[pb][32+pu] + bhN));
        hloc = (1.f-z)*n + z*hloc;
        st_u16_c(&hdd[(size_t)pb*H_ + u], (unsigned)f2bf(hloc));
        Xfc[((size_t)pb*TY_ + t)*H_ + u] = f2bf(hloc + sxv);
      }
      __syncthreads();   // drain h stores
      if (tid==0) __hip_atomic_store(&Hf[g], t+1, __ATOMIC_RELAXED, __HIP_MEMORY_SCOPE_AGENT);
    }
  }
}

extern "C" void kernel_launch(void* const* d_in, const int* in_sizes, int n_in,
                              void* d_out, int out_size, void* d_ws, size_t ws_size,
                              hipStream_t stream) {
  const int*   x     = (const int*)d_in[0];
  const int*   y     = (const int*)d_in[1];
  const float* emb   = (const float*)d_in[2];
  const float* eWih  = (const float*)d_in[3];
  const float* eWhh  = (const float*)d_in[4];
  const float* eBih  = (const float*)d_in[5];
  const float* eBhh  = (const float*)d_in[6];
  const float* dWih  = (const float*)d_in[7];
  const float* dWhh  = (const float*)d_in[8];
  const float* dBih  = (const float*)d_in[9];
  const float* dBhh  = (const float*)d_in[10];
  const float* hinit = (const float*)d_in[11];
  const float* fcW   = (const float*)d_in[12];
  const float* fcB   = (const float*)d_in[13];
  float* out = (float*)d_out;
  (void)in_sizes; (void)n_in; (void)out_size; (void)ws_size;

  char* p = (char*)d_ws;
  auto take = [&](size_t bytes)->char*{ char* r = p; p += (bytes + 255) & ~(size_t)255; return r; };
  u16* Wfc_bf   = (u16*)take((size_t)V_*H_*2);
  u16* ex_bf    = (u16*)take((size_t)B_*TX_*E_*2);
  u16* eWih_bf  = (u16*)take((size_t)G3_*E_*2);
  u16* Gx_bf    = (u16*)take((size_t)B_*TX_*G3_*2);
  u16* eh_bf    = (u16*)take((size_t)B_*TX_*H_*2);
  u16* embY_bf  = (u16*)take((size_t)4096*E_*2);
  u16* dWihE_bf = (u16*)take((size_t)G3_*E_*2);
  u16* Gy_bf    = (u16*)take((size_t)4096*G3_*2);
  u16* Xfc_bf   = (u16*)take((size_t)4096*H_*2);
  u16* eWhh_bf  = (u16*)take((size_t)G3_*H_*2);
  u16* dWhh_bf  = (u16*)take((size_t)G3_*H_*2);
  u16* dWihS_bf = (u16*)take((size_t)G3_*H_*2);
  u16* hgd      = (u16*)take((size_t)2*B_*H_*2);
  u16* hdd      = (u16*)take((size_t)B_*H_*2);
  u16* sxb      = (u16*)take((size_t)B_*H_*2);
  float* part   = (float*)take((size_t)NA_*H_*4);
  float* statsg = (float*)take((size_t)NA_*2*4);
  int* flagsE   = (int*)take(256);
  int* ctrl     = (int*)take(4096);
  int* Sf = ctrl, *Pf = ctrl+128, *Xf = ctrl+256, *Hf = ctrl+288;

  hipMemsetAsync(flagsE, 0, 256, stream);
  hipMemsetAsync(ctrl, 0, 4096, stream);
  hipMemsetAsync(hgd, 0, (size_t)2*B_*H_*2, stream);
  hipMemsetAsync(hdd, 0, (size_t)B_*H_*2, stream);

  cvt_rows<<<dim3(V_),  dim3(256), 0, stream>>>(fcW,  H_, 0, Wfc_bf,   H_);
  cvt_rows<<<dim3(G3_), dim3(256), 0, stream>>>(eWih, E_, 0, eWih_bf,  E_);
  cvt_rows<<<dim3(G3_), dim3(256), 0, stream>>>(dWih, E_+H_, 0, dWihE_bf, E_);
  cvt_rows<<<dim3(G3_), dim3(256), 0, stream>>>(eWhh, H_, 0, eWhh_bf,  H_);
  cvt_rows<<<dim3(G3_), dim3(256), 0, stream>>>(dWhh, H_, 0, dWhh_bf,  H_);
  cvt_rows<<<dim3(G3_), dim3(256), 0, stream>>>(dWih, E_+H_, E_, dWihS_bf, H_);

  gather_embed<<<dim3(B_*TX_), dim3(E_), 0, stream>>>(emb, x, ex_bf, TX_, TX_);
  gather_embed<<<dim3(B_*TY_), dim3(E_), 0, stream>>>(emb, y, embY_bf, TY_, 128);

  gemm_bf16<<<dim3(B_*TX_/128, G3_/128), dim3(256), 0, stream>>>(
      ex_bf, E_, eWih_bf, E_, Gx_bf, G3_, eBih, B_*TX_, E_, 1);
  gemm_bf16<<<dim3(32, G3_/128), dim3(256), 0, stream>>>(
      embY_bf, E_, dWihE_bf, E_, Gy_bf, G3_, dBih, B_*TY_, E_, 1);

  enc_v2<<<dim3(32), dim3(512), 0, stream>>>(Gx_bf, eWhh_bf, eBhh, eh_bf, hgd, flagsE);

  dec_v3<<<dim3(NA_+NW_), dim3(512), 0, stream>>>(eh_bf, Gy_bf, dWihS_bf, dWhh_bf,
                                                  dBhh, hinit, sxb, hdd, part, statsg,
                                                  Xfc_bf, Sf, Pf, Xf, Hf);

  gemm_bf16<<<dim3(32, V_/128), dim3(256), 0, stream>>>(
      Xfc_bf, H_, Wfc_bf, H_, out, V_, fcB, B_*TY_, H_, 0);
}

// Round 11
// 3293.036 us; speedup vs baseline: 21.7388x; 1.1067x over previous
//
#include <hip/hip_runtime.h>
#include <hip/hip_bf16.h>

// Seq2Seq GRU+attention, MI355X. Round 11: cut dec flag-chain 4->3 hops
// (merge stats into partial exchange; Sf eliminated) + overlap W's gH MFMA
// with attention phase (needs Hf wait + double-buffered hdd).
// r10 base: 128 A-blocks with LDS-resident eh quarters, 32 W-blocks.

#define B_  32
#define TX_ 512
#define TY_ 127
#define E_  256
#define H_  512
#define G3_ 1536
#define V_  32000
#define NA_ 128
#define NW_ 32

typedef unsigned short u16;
typedef short short8 __attribute__((ext_vector_type(8)));
typedef float f32x4 __attribute__((ext_vector_type(4)));
typedef float f32x2 __attribute__((ext_vector_type(2)));
typedef unsigned int u32x4 __attribute__((ext_vector_type(4)));

__device__ __forceinline__ float bfu(u16 h){ union{unsigned u; float f;} x; x.u=((unsigned)h)<<16; return x.f; }
__device__ __forceinline__ u16 f2bf(float f){ union{float f; unsigned u;} v; v.f=f; unsigned r=v.u+0x7fffu+((v.u>>16)&1u); return (u16)(r>>16); }
__device__ __forceinline__ float sigm(float x){ return 1.f/(1.f+__expf(-x)); }
__device__ __forceinline__ float tanh_f(float x){ return 1.f - 2.f/(__expf(2.f*x)+1.f); }

// ---- L2-bypass (coherent-point) accessors ----
__device__ __forceinline__ u32x4 ld16_c(const void* p){
  u32x4 r;
  asm volatile("global_load_dwordx4 %0, %1, off sc0 sc1\n\ts_waitcnt vmcnt(0)"
               : "=v"(r) : "v"(p) : "memory");
  return r;
}
__device__ __forceinline__ f32x2 ld8_c(const void* p){
  f32x2 r;
  asm volatile("global_load_dwordx2 %0, %1, off sc0 sc1\n\ts_waitcnt vmcnt(0)"
               : "=v"(r) : "v"(p) : "memory");
  return r;
}
__device__ __forceinline__ void ld3f_c(const float* p0, const float* p1, const float* p2,
                                       float& a, float& b, float& c){
  asm volatile(
    "global_load_dword %0, %3, off sc0 sc1\n\t"
    "global_load_dword %1, %4, off sc0 sc1\n\t"
    "global_load_dword %2, %5, off sc0 sc1\n\t"
    "s_waitcnt vmcnt(0)"
    : "=&v"(a),"=&v"(b),"=&v"(c)
    : "v"(p0),"v"(p1),"v"(p2) : "memory");
}
__device__ __forceinline__ void st_u16_c(void* p, unsigned v){
  asm volatile("global_store_short %0, %1, off sc0 sc1" :: "v"(p), "v"(v) : "memory");
}
__device__ __forceinline__ void st8_c(void* p, float a, float b){
  f32x2 v; v.x=a; v.y=b;
  asm volatile("global_store_dwordx2 %0, %1, off sc0 sc1" :: "v"(p), "v"(v) : "memory");
}
__device__ __forceinline__ void st4f_c(void* p, float v){
  asm volatile("global_store_dword %0, %1, off sc0 sc1" :: "v"(p), "v"(v) : "memory");
}

__device__ __forceinline__ void spin_rel(int* p, int tgt){
  int n = 0;
  while (__hip_atomic_load(p, __ATOMIC_RELAXED, __HIP_MEMORY_SCOPE_AGENT) < tgt){
    __builtin_amdgcn_s_sleep(1);
    if (++n > (1<<22)) break;   // bounded: bug -> wrong output, not hang
  }
}

// flag barrier over 32 blocks (encoder)
__device__ __forceinline__ void flagbar(int* flags, int target){
  __syncthreads();
  if (threadIdx.x == 0)
    __hip_atomic_store(&flags[blockIdx.x], target, __ATOMIC_RELAXED, __HIP_MEMORY_SCOPE_AGENT);
  if (threadIdx.x < 32) spin_rel(&flags[threadIdx.x], target);
  __syncthreads();
  asm volatile("" ::: "memory");
}

// stage [32][512] bf16 (sc1-written) global -> stgl LDS via bypass loads
__device__ __forceinline__ void stage4_c(u16 (*stgl)[520], const u16* src, int tid){
  const u16* b0 = src + (size_t)(tid>>6)*H_ + (tid&63)*8;
  const u16* b1 = b0 + (size_t)8*H_;
  const u16* b2 = b0 + (size_t)16*H_;
  const u16* b3 = b0 + (size_t)24*H_;
  u32x4 q0,q1,q2,q3;
  asm volatile(
    "global_load_dwordx4 %0, %4, off sc0 sc1\n\t"
    "global_load_dwordx4 %1, %5, off sc0 sc1\n\t"
    "global_load_dwordx4 %2, %6, off sc0 sc1\n\t"
    "global_load_dwordx4 %3, %7, off sc0 sc1\n\t"
    "s_waitcnt vmcnt(0)"
    : "=&v"(q0),"=&v"(q1),"=&v"(q2),"=&v"(q3)
    : "v"(b0),"v"(b1),"v"(b2),"v"(b3) : "memory");
  int r = tid>>6, c = (tid&63)*8;
  *(u32x4*)&stgl[r][c]    = q0;
  *(u32x4*)&stgl[r+8][c]  = q1;
  *(u32x4*)&stgl[r+16][c] = q2;
  *(u32x4*)&stgl[r+24][c] = q3;
}

// ---------- f32 -> bf16 row converter ----------
__global__ void cvt_rows(const float* __restrict__ src, int sld, int soff,
                         u16* __restrict__ dst, int cols){
  int r = blockIdx.x;
  const float* s = src + (size_t)r*sld + soff;
  u16* d = dst + (size_t)r*cols;
  for (int c = threadIdx.x; c < cols; c += blockDim.x) d[c] = f2bf(s[c]);
}

// ---------- embedding gather -> bf16 rows ----------
__global__ void gather_embed(const float* __restrict__ emb, const int* __restrict__ idx,
                             u16* __restrict__ dst, int rows_per_b, int ld){
  int m = blockIdx.x;
  int bb = m / rows_per_b, tt = m - bb*rows_per_b;
  int id = idx[bb*ld + tt];
  dst[(size_t)m*E_ + threadIdx.x] = f2bf(emb[(size_t)id*E_ + threadIdx.x]);
}

// ---------- bf16 MFMA GEMM: C[M,N] = A[M,K] @ B[N,K]^T + bias ----------
__global__ __launch_bounds__(256) void gemm_bf16(
    const u16* __restrict__ A, int lda, const u16* __restrict__ Bm, int ldb,
    void* __restrict__ Cout, int ldc, const float* __restrict__ bias,
    int M, int K, int out_bf16)
{
  int wave = threadIdx.x >> 6, lane = threadIdx.x & 63;
  int m0 = blockIdx.x*128 + (wave>>1)*64;
  int n0 = blockIdx.y*128 + (wave&1)*64;
  int lr = lane & 15, lk = (lane>>4)*8;
  f32x4 acc[4][4];
  #pragma unroll
  for (int i=0;i<4;++i)
    #pragma unroll
    for (int j=0;j<4;++j) acc[i][j] = (f32x4){0.f,0.f,0.f,0.f};
  for (int k0=0; k0<K; k0+=32){
    short8 af[4], bfv[4];
    #pragma unroll
    for (int i=0;i<4;++i){
      int row = m0 + i*16 + lr; if (row > M-1) row = M-1;
      af[i] = *(const short8*)(A + (size_t)row*lda + k0 + lk);
    }
    #pragma unroll
    for (int j=0;j<4;++j){
      int col = n0 + j*16 + lr;
      bfv[j] = *(const short8*)(Bm + (size_t)col*ldb + k0 + lk);
    }
    #pragma unroll
    for (int i=0;i<4;++i)
      #pragma unroll
      for (int j=0;j<4;++j)
        acc[i][j] = __builtin_amdgcn_mfma_f32_16x16x32_bf16(af[i], bfv[j], acc[i][j], 0,0,0);
  }
  int rbase = (lane>>4)*4;
  #pragma unroll
  for (int i=0;i<4;++i)
    #pragma unroll
    for (int r=0;r<4;++r){
      int row = m0 + i*16 + rbase + r;
      if (row < M){
        #pragma unroll
        for (int j=0;j<4;++j){
          int col = n0 + j*16 + lr;
          float v = acc[i][j][r] + bias[col];
          if (out_bf16) ((u16*)Cout)[(size_t)row*ldc + col] = f2bf(v);
          else          ((float*)Cout)[(size_t)row*ldc + col] = v;
        }
      }
    }
}

// ---------- encoder: 32 blocks x 512 thr (r8-proven, untouched) ----------
__global__ __launch_bounds__(512,2) void enc_v2(
    const u16* __restrict__ Gx, const u16* __restrict__ Whh_bf,
    const float* __restrict__ bhh, u16* __restrict__ eh,
    u16* __restrict__ hgd, int* flags)
{
  __shared__ __align__(16) u16 stgl[32][520];
  __shared__ __align__(16) float gH[32][52];
  int tid = threadIdx.x, g = blockIdx.x;
  int wave = tid>>6, lane = tid&63;
  int pb = tid>>4, pu = tid&15, u = g*16 + pu;

  short8 fH[16];
  int mt = wave/3, nt = wave%3;
  if (wave < 6){
    int row = nt*H_ + g*16 + (lane&15);
    int kb = (lane>>4)*8;
    #pragma unroll
    for (int ks=0;ks<16;++ks)
      fH[ks] = *(const short8*)(Whh_bf + (size_t)row*H_ + ks*32 + kb);
  }
  float bhR = bhh[u], bhZ = bhh[u+H_], bhN = bhh[u+2*H_];
  float hloc = 0.f;

  for (int t=0;t<TX_;++t){
    size_t gxb = ((size_t)pb*TX_ + t)*G3_;
    float iR = bfu(Gx[gxb+u]), iZ = bfu(Gx[gxb+H_+u]), iN = bfu(Gx[gxb+2*H_+u]);
    stage4_c(stgl, hgd + (size_t)(t&1)*B_*H_, tid);
    __syncthreads();
    if (wave < 6){
      f32x4 acc = (f32x4){0.f,0.f,0.f,0.f};
      int ar = mt*16 + (lane&15), ak = (lane>>4)*8;
      #pragma unroll
      for (int ks=0;ks<16;++ks)
        acc = __builtin_amdgcn_mfma_f32_16x16x32_bf16(*(const short8*)&stgl[ar][ks*32+ak], fH[ks], acc, 0,0,0);
      int dr = mt*16 + ((lane>>4)<<2), dc = nt*16 + (lane&15);
      #pragma unroll
      for (int r=0;r<4;++r) gH[dr+r][dc] = acc[r];
    }
    __syncthreads();
    float r = sigm(iR + gH[pb][pu]    + bhR);
    float z = sigm(iZ + gH[pb][16+pu] + bhZ);
    float n = tanh_f(iN + r*(gH[pb][32+pu] + bhN));
    hloc = (1.f-z)*n + z*hloc;
    u16 hb = f2bf(hloc);
    st_u16_c(&hgd[(size_t)((t+1)&1)*B_*H_ + (size_t)pb*H_ + u], (unsigned)hb);
    eh[((size_t)pb*TX_ + t)*H_ + u] = hb;
    flagbar(flags, t+1);
  }
}

// ---------- decoder: 160 blocks x 512 thr (128 A + 32 W), 3-hop chain ----------
__global__ __launch_bounds__(512,2) void dec_v4(
    const u16* __restrict__ eh, const u16* __restrict__ Gy,
    const u16* __restrict__ WihS_bf, const u16* __restrict__ Whh_bf,
    const float* __restrict__ dbhh, const float* __restrict__ hinit,
    u16* __restrict__ sxb, u16* __restrict__ hdd2,
    float* __restrict__ part, float* __restrict__ statsg,
    u16* __restrict__ Xfc,
    int* Pf, int* Xf, int* Hf)
{
  struct AS {
    u16   ehq[128][512];   // 128KB, swizzled: col ^= (row&7)<<3
    u16   oxb[512];
    float sc[128];
    float pt[8][512];      // 16KB PV partials
    float red[16];         // [0..7] max-slots, [8..15] sum-slots
    float st4[8];          // sibling stats (m,l) x3
  };
  struct WS { u16 stgl[32][520]; float gS[32][52]; float gH[32][52]; };
  __shared__ __align__(16) char smem_[sizeof(AS)];
  int tid = threadIdx.x;
  int wave = tid>>6, lane = tid&63;

  if (blockIdx.x < NA_){
    // ===== role A: attention quarter (batch b, chunk q) =====
    AS& S = *(AS*)smem_;
    int b = blockIdx.x >> 2, q = blockIdx.x & 3;
    { // preload eh quarter, swizzled (once; normal cached loads)
      const u16* ehg = eh + ((size_t)b*TX_ + q*128)*H_;
      int row = tid>>2, c0 = (tid&3)*128;
      #pragma unroll
      for (int j=0;j<16;++j){
        int u0 = c0 + j*8;
        uint4 v = *(const uint4*)(ehg + (size_t)row*H_ + u0);
        *(uint4*)&S.ehq[row][u0 ^ ((row&7)<<3)] = v;
      }
    }
    __syncthreads();
    bool bl = (lane&15) == 0;
    for (int t=0;t<TY_;++t){
      // ---- ox = h(t-1) from hdd2[t&1] ----
      if (t > 0){
        if (tid < NW_) spin_rel(&Hf[tid], t);
        __syncthreads();
        asm volatile("" ::: "memory");
        if (tid < 64){
          u32x4 qv = ld16_c(hdd2 + (size_t)(t&1)*B_*H_ + (size_t)b*H_ + tid*8);
          *(u32x4*)&S.oxb[tid*8] = qv;
        }
      } else {
        S.oxb[tid] = f2bf(hinit[tid]);
      }
      __syncthreads();
      // ---- scores: rows [wave*16, wave*16+16) from resident LDS ----
      {
        f32x4 acS = (f32x4){0.f,0.f,0.f,0.f};
        int arow = wave*16 + (lane&15);
        int swz = (arow&7)<<3;
        #pragma unroll
        for (int kt=0;kt<16;++kt){
          short8 bf = (short8){0,0,0,0,0,0,0,0};
          if (bl) bf = *(const short8*)&S.oxb[kt*32 + (lane>>4)*8];
          short8 af_ = *(const short8*)&S.ehq[arow][(kt*32 + (lane>>4)*8) ^ swz];
          acS = __builtin_amdgcn_mfma_f32_16x16x32_bf16(af_, bf, acS, 0,0,0);
        }
        if (bl){
          #pragma unroll
          for (int r=0;r<4;++r) S.sc[wave*16 + (lane>>4)*4 + r] = acS[r];
        }
      }
      __syncthreads();
      // ---- local stats: mq, exp -> sc, lq ----
      float mq, lq;
      {
        float v = (tid<128) ? S.sc[tid] : -3e38f;
        #pragma unroll
        for (int o=32;o>0;o>>=1) v = fmaxf(v, __shfl_xor(v, o));
        if (lane==0) S.red[wave] = v;
        __syncthreads();
        mq = fmaxf(S.red[0], S.red[1]);
        float e = 0.f;
        if (tid<128){ e = __expf(S.sc[tid] - mq); S.sc[tid] = e; }
        float s2 = e;
        #pragma unroll
        for (int o=32;o>0;o>>=1) s2 += __shfl_xor(s2, o);
        if (lane==0) S.red[8+wave] = s2;
        __syncthreads();
        lq = S.red[8] + S.red[9];
      }
      // ---- PV partial (local-max-referenced, unnormalized) ----
      int u0 = lane*8, tseg = wave;
      f32x4 aLo = (f32x4){0.f,0.f,0.f,0.f}, aHi = (f32x4){0.f,0.f,0.f,0.f};
      #pragma unroll
      for (int j=0;j<16;++j){
        int tp = tseg*16 + j;
        short8 ev = *(const short8*)&S.ehq[tp][u0 ^ ((tp&7)<<3)];
        float av = S.sc[tp];
        aLo[0] = fmaf(bfu((u16)ev[0]), av, aLo[0]);
        aLo[1] = fmaf(bfu((u16)ev[1]), av, aLo[1]);
        aLo[2] = fmaf(bfu((u16)ev[2]), av, aLo[2]);
        aLo[3] = fmaf(bfu((u16)ev[3]), av, aLo[3]);
        aHi[0] = fmaf(bfu((u16)ev[4]), av, aHi[0]);
        aHi[1] = fmaf(bfu((u16)ev[5]), av, aHi[1]);
        aHi[2] = fmaf(bfu((u16)ev[6]), av, aHi[2]);
        aHi[3] = fmaf(bfu((u16)ev[7]), av, aHi[3]);
      }
      *(f32x4*)&S.pt[tseg][u0]   = aLo;
      *(f32x4*)&S.pt[tseg][u0+4] = aHi;
      __syncthreads();
      float sv = 0.f;
      #pragma unroll
      for (int gsg=0; gsg<8; ++gsg) sv += S.pt[gsg][tid];
      if (q != 0){
        // publish partial + stats -> Pf  (single hop; no Sf)
        st4f_c(&part[(size_t)(b*4+q)*512 + tid], sv);
        if (tid==0) st8_c(&statsg[(size_t)(b*4+q)*2], mq, lq);
        __syncthreads();   // drain
        if (tid==0) __hip_atomic_store(&Pf[b*4+q], t+1, __ATOMIC_RELAXED, __HIP_MEMORY_SCOPE_AGENT);
      } else {
        // q0: combine all 4 quarters with rescaling
        if (tid < 3) spin_rel(&Pf[b*4+1+tid], t+1);
        __syncthreads();
        asm volatile("" ::: "memory");
        if (tid < 3){
          f32x2 r2 = ld8_c(&statsg[(size_t)(b*4+1+tid)*2]);
          S.st4[tid*2] = r2.x; S.st4[tid*2+1] = r2.y;
        }
        __syncthreads();
        float m1=S.st4[0], l1=S.st4[1], m2=S.st4[2], l2=S.st4[3], m3=S.st4[4], l3=S.st4[5];
        float gmax = fmaxf(fmaxf(mq,m1), fmaxf(m2,m3));
        float e0=__expf(mq-gmax), e1=__expf(m1-gmax), e2=__expf(m2-gmax), e3=__expf(m3-gmax);
        float inv = 1.f/(lq*e0 + l1*e1 + l2*e2 + l3*e3);
        float p1,p2,p3;
        ld3f_c(&part[(size_t)(b*4+1)*512 + tid], &part[(size_t)(b*4+2)*512 + tid],
               &part[(size_t)(b*4+3)*512 + tid], p1, p2, p3);
        float sx = (sv*e0 + p1*e1 + p2*e2 + p3*e3) * inv;
        st_u16_c(&sxb[(size_t)b*H_ + tid], (unsigned)f2bf(sx));
        __syncthreads();   // drain
        if (tid==0) __hip_atomic_store(&Xf[b], t+1, __ATOMIC_RELAXED, __HIP_MEMORY_SCOPE_AGENT);
      }
    }
  } else {
    // ===== role W: gates for units [16g,16g+16), all 32 batches =====
    WS& S = *(WS*)smem_;
    int g = blockIdx.x - NA_;
    int pb = tid>>4, pu = tid&15, u = g*16 + pu;
    short8 fS[16], fH[16];
    int mt = wave/3, nt = wave%3;
    if (wave < 6){
      int row = nt*H_ + g*16 + (lane&15);
      int kb = (lane>>4)*8;
      #pragma unroll
      for (int ks=0;ks<16;++ks){
        fS[ks] = *(const short8*)(WihS_bf + (size_t)row*H_ + ks*32 + kb);
        fH[ks] = *(const short8*)(Whh_bf  + (size_t)row*H_ + ks*32 + kb);
      }
    }
    float bhR = dbhh[u], bhZ = dbhh[u+H_], bhN = dbhh[u+2*H_];
    float hloc = 0.f;

    for (int t=0;t<TY_;++t){
      // Gy loads issued first (cached, overlap everything below)
      size_t gyb = ((size_t)pb*TY_ + t)*G3_;
      float iR = bfu(Gy[gyb+u]), iZ = bfu(Gy[gyb+H_+u]), iN = bfu(Gy[gyb+2*H_+u]);
      // ---- pre-Xf: gH from h(t-1) (overlaps A's attention phase) ----
      if (tid < NW_) spin_rel(&Hf[tid], t);
      __syncthreads();
      asm volatile("" ::: "memory");
      stage4_c(S.stgl, hdd2 + (size_t)(t&1)*B_*H_, tid);
      __syncthreads();
      int ar = mt*16 + (lane&15), ak = (lane>>4)*8;
      if (wave < 6){
        f32x4 acc = (f32x4){0.f,0.f,0.f,0.f};
        #pragma unroll
        for (int ks=0;ks<16;++ks)
          acc = __builtin_amdgcn_mfma_f32_16x16x32_bf16(*(const short8*)&S.stgl[ar][ks*32+ak], fH[ks], acc, 0,0,0);
        int dr = mt*16 + ((lane>>4)<<2), dc = nt*16 + (lane&15);
        #pragma unroll
        for (int r=0;r<4;++r) S.gH[dr+r][dc] = acc[r];
      }
      // ---- wait sx, then gS ----
      if (tid < 32) spin_rel(&Xf[tid], t+1);
      __syncthreads();           // also orders gH MFMA (stgl reads) before overwrite
      asm volatile("" ::: "memory");
      stage4_c(S.stgl, sxb, tid);
      __syncthreads();
      float sxv = bfu(S.stgl[pb][u]);
      if (wave < 6){
        f32x4 acc = (f32x4){0.f,0.f,0.f,0.f};
        #pragma unroll
        for (int ks=0;ks<16;++ks)
          acc = __builtin_amdgcn_mfma_f32_16x16x32_bf16(*(const short8*)&S.stgl[ar][ks*32+ak], fS[ks], acc, 0,0,0);
        int dr = mt*16 + ((lane>>4)<<2), dc = nt*16 + (lane&15);
        #pragma unroll
        for (int r=0;r<4;++r) S.gS[dr+r][dc] = acc[r];
      }
      __syncthreads();
      { // pointwise: i_n gets gS (sx part) UNSCALED; only gH_n (+bhh_n) r-scaled
        float r = sigm(iR + S.gS[pb][pu]    + S.gH[pb][pu]    + bhR);
        float z = sigm(iZ + S.gS[pb][16+pu] + S.gH[pb][16+pu] + bhZ);
        float n = tanh_f(iN + S.gS[pb][32+pu] + r*(S.gH[pb][32+pu] + bhN));
        hloc = (1.f-z)*n + z*hloc;
        st_u16_c(&hdd2[(size_t)((t+1)&1)*B_*H_ + (size_t)pb*H_ + u], (unsigned)f2bf(hloc));
        Xfc[((size_t)pb*TY_ + t)*H_ + u] = f2bf(hloc + sxv);
      }
      __syncthreads();   // drain h stores
      if (tid==0) __hip_atomic_store(&Hf[g], t+1, __ATOMIC_RELAXED, __HIP_MEMORY_SCOPE_AGENT);
    }
  }
}

extern "C" void kernel_launch(void* const* d_in, const int* in_sizes, int n_in,
                              void* d_out, int out_size, void* d_ws, size_t ws_size,
                              hipStream_t stream) {
  const int*   x     = (const int*)d_in[0];
  const int*   y     = (const int*)d_in[1];
  const float* emb   = (const float*)d_in[2];
  const float* eWih  = (const float*)d_in[3];
  const float* eWhh  = (const float*)d_in[4];
  const float* eBih  = (const float*)d_in[5];
  const float* eBhh  = (const float*)d_in[6];
  const float* dWih  = (const float*)d_in[7];
  const float* dWhh  = (const float*)d_in[8];
  const float* dBih  = (const float*)d_in[9];
  const float* dBhh  = (const float*)d_in[10];
  const float* hinit = (const float*)d_in[11];
  const float* fcW   = (const float*)d_in[12];
  const float* fcB   = (const float*)d_in[13];
  float* out = (float*)d_out;
  (void)in_sizes; (void)n_in; (void)out_size; (void)ws_size;

  char* p = (char*)d_ws;
  auto take = [&](size_t bytes)->char*{ char* r = p; p += (bytes + 255) & ~(size_t)255; return r; };
  u16* Wfc_bf   = (u16*)take((size_t)V_*H_*2);
  u16* ex_bf    = (u16*)take((size_t)B_*TX_*E_*2);
  u16* eWih_bf  = (u16*)take((size_t)G3_*E_*2);
  u16* Gx_bf    = (u16*)take((size_t)B_*TX_*G3_*2);
  u16* eh_bf    = (u16*)take((size_t)B_*TX_*H_*2);
  u16* embY_bf  = (u16*)take((size_t)4096*E_*2);
  u16* dWihE_bf = (u16*)take((size_t)G3_*E_*2);
  u16* Gy_bf    = (u16*)take((size_t)4096*G3_*2);
  u16* Xfc_bf   = (u16*)take((size_t)4096*H_*2);
  u16* eWhh_bf  = (u16*)take((size_t)G3_*H_*2);
  u16* dWhh_bf  = (u16*)take((size_t)G3_*H_*2);
  u16* dWihS_bf = (u16*)take((size_t)G3_*H_*2);
  u16* hgd      = (u16*)take((size_t)2*B_*H_*2);
  u16* hdd2     = (u16*)take((size_t)2*B_*H_*2);
  u16* sxb      = (u16*)take((size_t)B_*H_*2);
  float* part   = (float*)take((size_t)NA_*H_*4);
  float* statsg = (float*)take((size_t)NA_*2*4);
  int* flagsE   = (int*)take(256);
  int* ctrl     = (int*)take(4096);
  int* Pf = ctrl, *Xf = ctrl+128, *Hf = ctrl+160;

  hipMemsetAsync(flagsE, 0, 256, stream);
  hipMemsetAsync(ctrl, 0, 4096, stream);
  hipMemsetAsync(hgd, 0, (size_t)2*B_*H_*2, stream);
  hipMemsetAsync(hdd2, 0, (size_t)2*B_*H_*2, stream);

  cvt_rows<<<dim3(V_),  dim3(256), 0, stream>>>(fcW,  H_, 0, Wfc_bf,   H_);
  cvt_rows<<<dim3(G3_), dim3(256), 0, stream>>>(eWih, E_, 0, eWih_bf,  E_);
  cvt_rows<<<dim3(G3_), dim3(256), 0, stream>>>(dWih, E_+H_, 0, dWihE_bf, E_);
  cvt_rows<<<dim3(G3_), dim3(256), 0, stream>>>(eWhh, H_, 0, eWhh_bf,  H_);
  cvt_rows<<<dim3(G3_), dim3(256), 0, stream>>>(dWhh, H_, 0, dWhh_bf,  H_);
  cvt_rows<<<dim3(G3_), dim3(256), 0, stream>>>(dWih, E_+H_, E_, dWihS_bf, H_);

  gather_embed<<<dim3(B_*TX_), dim3(E_), 0, stream>>>(emb, x, ex_bf, TX_, TX_);
  gather_embed<<<dim3(B_*TY_), dim3(E_), 0, stream>>>(emb, y, embY_bf, TY_, 128);

  gemm_bf16<<<dim3(B_*TX_/128, G3_/128), dim3(256), 0, stream>>>(
      ex_bf, E_, eWih_bf, E_, Gx_bf, G3_, eBih, B_*TX_, E_, 1);
  gemm_bf16<<<dim3(32, G3_/128), dim3(256), 0, stream>>>(
      embY_bf, E_, dWihE_bf, E_, Gy_bf, G3_, dBih, B_*TY_, E_, 1);

  enc_v2<<<dim3(32), dim3(512), 0, stream>>>(Gx_bf, eWhh_bf, eBhh, eh_bf, hgd, flagsE);

  dec_v4<<<dim3(NA_+NW_), dim3(512), 0, stream>>>(eh_bf, Gy_bf, dWihS_bf, dWhh_bf,
                                                  dBhh, hinit, sxb, hdd2, part, statsg,
                                                  Xfc_bf, Pf, Xf, Hf);

  gemm_bf16<<<dim3(32, V_/128), dim3(256), 0, stream>>>(
      Xfc_bf, H_, Wfc_bf, H_, out, V_, fcB, B_*TY_, H_, 0);
}

// Round 13
// 2684.471 us; speedup vs baseline: 26.6669x; 1.2267x over previous
//
#include <hip/hip_runtime.h>
#include <hip/hip_bf16.h>

// Seq2Seq GRU+attention, MI355X. Round 13: r12 + FC A-band load fix
// (it2<16, was 8 -> half the band was uninitialized LDS -> NaN) and
// NF_ 96->80 (grid 240: 16-CU residency slack; FC is ticket-elastic).

#define B_  32
#define TX_ 512
#define TY_ 127
#define E_  256
#define H_  512
#define G3_ 1536
#define V_  32000
#define NA_ 128
#define NW_ 32
#define NF_ 80

typedef unsigned short u16;
typedef short short8 __attribute__((ext_vector_type(8)));
typedef float f32x4 __attribute__((ext_vector_type(4)));
typedef float f32x2 __attribute__((ext_vector_type(2)));
typedef unsigned int u32x4 __attribute__((ext_vector_type(4)));

__device__ __forceinline__ float bfu(u16 h){ union{unsigned u; float f;} x; x.u=((unsigned)h)<<16; return x.f; }
__device__ __forceinline__ u16 f2bf(float f){ union{float f; unsigned u;} v; v.f=f; unsigned r=v.u+0x7fffu+((v.u>>16)&1u); return (u16)(r>>16); }
__device__ __forceinline__ float sigm(float x){ return 1.f/(1.f+__expf(-x)); }
__device__ __forceinline__ float tanh_f(float x){ return 1.f - 2.f/(__expf(2.f*x)+1.f); }

// ---- L2-bypass (coherent-point) accessors ----
__device__ __forceinline__ u32x4 ld16_c(const void* p){
  u32x4 r;
  asm volatile("global_load_dwordx4 %0, %1, off sc0 sc1\n\ts_waitcnt vmcnt(0)"
               : "=v"(r) : "v"(p) : "memory");
  return r;
}
__device__ __forceinline__ void st_u16_c(void* p, unsigned v){
  asm volatile("global_store_short %0, %1, off sc0 sc1" :: "v"(p), "v"(v) : "memory");
}
__device__ __forceinline__ void st8_c(void* p, float a, float b){
  f32x2 v; v.x=a; v.y=b;
  asm volatile("global_store_dwordx2 %0, %1, off sc0 sc1" :: "v"(p), "v"(v) : "memory");
}
__device__ __forceinline__ void st4f_c(void* p, float v){
  asm volatile("global_store_dword %0, %1, off sc0 sc1" :: "v"(p), "v"(v) : "memory");
}

__device__ __forceinline__ void spin_rel(int* p, int tgt){
  int n = 0;
  while (__hip_atomic_load(p, __ATOMIC_RELAXED, __HIP_MEMORY_SCOPE_AGENT) < tgt){
    __builtin_amdgcn_s_sleep(1);
    if (++n > (1<<22)) break;   // bounded: bug -> wrong output, not hang
  }
}
__device__ __forceinline__ void spin_rel_slow(int* p, int tgt){
  int n = 0;
  while (__hip_atomic_load(p, __ATOMIC_RELAXED, __HIP_MEMORY_SCOPE_AGENT) < tgt){
    __builtin_amdgcn_s_sleep(16);
    if (++n > (1<<20)) break;
  }
}

// stage [32][512] bf16 (sc1-written) global -> stgl LDS via bypass loads
__device__ __forceinline__ void stage4_c(u16 (*stgl)[520], const u16* src, int tid){
  const u16* b0 = src + (size_t)(tid>>6)*H_ + (tid&63)*8;
  const u16* b1 = b0 + (size_t)8*H_;
  const u16* b2 = b0 + (size_t)16*H_;
  const u16* b3 = b0 + (size_t)24*H_;
  u32x4 q0,q1,q2,q3;
  asm volatile(
    "global_load_dwordx4 %0, %4, off sc0 sc1\n\t"
    "global_load_dwordx4 %1, %5, off sc0 sc1\n\t"
    "global_load_dwordx4 %2, %6, off sc0 sc1\n\t"
    "global_load_dwordx4 %3, %7, off sc0 sc1\n\t"
    "s_waitcnt vmcnt(0)"
    : "=&v"(q0),"=&v"(q1),"=&v"(q2),"=&v"(q3)
    : "v"(b0),"v"(b1),"v"(b2),"v"(b3) : "memory");
  int r = tid>>6, c = (tid&63)*8;
  *(u32x4*)&stgl[r][c]    = q0;
  *(u32x4*)&stgl[r+8][c]  = q1;
  *(u32x4*)&stgl[r+16][c] = q2;
  *(u32x4*)&stgl[r+24][c] = q3;
}

// ---------- f32 -> bf16 row converter ----------
__global__ void cvt_rows(const float* __restrict__ src, int sld, int soff,
                         u16* __restrict__ dst, int cols){
  int r = blockIdx.x;
  const float* s = src + (size_t)r*sld + soff;
  u16* d = dst + (size_t)r*cols;
  for (int c = threadIdx.x; c < cols; c += blockDim.x) d[c] = f2bf(s[c]);
}

// ---------- embedding gather -> bf16 rows ----------
__global__ void gather_embed(const float* __restrict__ emb, const int* __restrict__ idx,
                             u16* __restrict__ dst, int rows_per_b, int ld){
  int m = blockIdx.x;
  int bb = m / rows_per_b, tt = m - bb*rows_per_b;
  int id = idx[bb*ld + tt];
  dst[(size_t)m*E_ + threadIdx.x] = f2bf(emb[(size_t)id*E_ + threadIdx.x]);
}

// ---------- bf16 MFMA GEMM (Gx/Gy precomputes) ----------
__global__ __launch_bounds__(256) void gemm_bf16(
    const u16* __restrict__ A, int lda, const u16* __restrict__ Bm, int ldb,
    void* __restrict__ Cout, int ldc, const float* __restrict__ bias,
    int M, int K, int out_bf16)
{
  int wave = threadIdx.x >> 6, lane = threadIdx.x & 63;
  int m0 = blockIdx.x*128 + (wave>>1)*64;
  int n0 = blockIdx.y*128 + (wave&1)*64;
  int lr = lane & 15, lk = (lane>>4)*8;
  f32x4 acc[4][4];
  #pragma unroll
  for (int i=0;i<4;++i)
    #pragma unroll
    for (int j=0;j<4;++j) acc[i][j] = (f32x4){0.f,0.f,0.f,0.f};
  for (int k0=0; k0<K; k0+=32){
    short8 af[4], bfv[4];
    #pragma unroll
    for (int i=0;i<4;++i){
      int row = m0 + i*16 + lr; if (row > M-1) row = M-1;
      af[i] = *(const short8*)(A + (size_t)row*lda + k0 + lk);
    }
    #pragma unroll
    for (int j=0;j<4;++j){
      int col = n0 + j*16 + lr;
      bfv[j] = *(const short8*)(Bm + (size_t)col*ldb + k0 + lk);
    }
    #pragma unroll
    for (int i=0;i<4;++i)
      #pragma unroll
      for (int j=0;j<4;++j)
        acc[i][j] = __builtin_amdgcn_mfma_f32_16x16x32_bf16(af[i], bfv[j], acc[i][j], 0,0,0);
  }
  int rbase = (lane>>4)*4;
  #pragma unroll
  for (int i=0;i<4;++i)
    #pragma unroll
    for (int r=0;r<4;++r){
      int row = m0 + i*16 + rbase + r;
      if (row < M){
        #pragma unroll
        for (int j=0;j<4;++j){
          int col = n0 + j*16 + lr;
          float v = acc[i][j][r] + bias[col];
          if (out_bf16) ((u16*)Cout)[(size_t)row*ldc + col] = f2bf(v);
          else          ((float*)Cout)[(size_t)row*ldc + col] = v;
        }
      }
    }
}

// ---------- encoder: 32 blocks x 512 thr, rotated loop ----------
__global__ __launch_bounds__(512,2) void enc_v3(
    const u16* __restrict__ Gx, const u16* __restrict__ Whh_bf,
    const float* __restrict__ bhh, u16* __restrict__ eh,
    u16* __restrict__ hgd, int* flags)
{
  __shared__ __align__(16) u16 stgl[32][520];
  __shared__ __align__(16) float gH[32][52];
  int tid = threadIdx.x, g = blockIdx.x;
  int wave = tid>>6, lane = tid&63;
  int pb = tid>>4, pu = tid&15, u = g*16 + pu;

  short8 fH[16];
  int mt = wave/3, nt = wave%3;
  if (wave < 6){
    int row = nt*H_ + g*16 + (lane&15);
    int kb = (lane>>4)*8;
    #pragma unroll
    for (int ks=0;ks<16;++ks)
      fH[ks] = *(const short8*)(Whh_bf + (size_t)row*H_ + ks*32 + kb);
  }
  float bhR = bhh[u], bhZ = bhh[u+H_], bhN = bhh[u+2*H_];
  float hloc = 0.f;
  size_t gx0 = (size_t)pb*TX_*G3_;
  float iR = bfu(Gx[gx0+u]), iZ = bfu(Gx[gx0+H_+u]), iN = bfu(Gx[gx0+2*H_+u]);

  for (int t=0;t<TX_;++t){
    if (t > 0){
      if (tid < 32) spin_rel(&flags[tid], t);
      __syncthreads();
      asm volatile("" ::: "memory");
    }
    stage4_c(stgl, hgd + (size_t)(t&1)*B_*H_, tid);
    __syncthreads();
    if (wave < 6){
      f32x4 acc = (f32x4){0.f,0.f,0.f,0.f};
      int ar = mt*16 + (lane&15), ak = (lane>>4)*8;
      #pragma unroll
      for (int ks=0;ks<16;++ks)
        acc = __builtin_amdgcn_mfma_f32_16x16x32_bf16(*(const short8*)&stgl[ar][ks*32+ak], fH[ks], acc, 0,0,0);
      int dr = mt*16 + ((lane>>4)<<2), dc = nt*16 + (lane&15);
      #pragma unroll
      for (int r=0;r<4;++r) gH[dr+r][dc] = acc[r];
    }
    __syncthreads();
    float r = sigm(iR + gH[pb][pu]    + bhR);
    float z = sigm(iZ + gH[pb][16+pu] + bhZ);
    float n = tanh_f(iN + r*(gH[pb][32+pu] + bhN));
    hloc = (1.f-z)*n + z*hloc;
    u16 hb = f2bf(hloc);
    st_u16_c(&hgd[(size_t)((t+1)&1)*B_*H_ + (size_t)pb*H_ + u], (unsigned)hb);
    __syncthreads();   // drain h stores
    if (tid == 0)
      __hip_atomic_store(&flags[blockIdx.x], t+1, __ATOMIC_RELAXED, __HIP_MEMORY_SCOPE_AGENT);
    // post-arrive work, hidden inside other blocks' wait:
    eh[((size_t)pb*TX_ + t)*H_ + u] = hb;
    if (t+1 < TX_){
      size_t g2 = ((size_t)pb*TX_ + (t+1))*G3_;
      iR = bfu(Gx[g2+u]); iZ = bfu(Gx[g2+H_+u]); iN = bfu(Gx[g2+2*H_+u]);
    }
  }
}

// ---------- decoder+FC: 240 blocks x 512 thr (128 A + 32 W + 80 FC) ----------
__global__ __launch_bounds__(512,2) void dec_v5(
    const u16* __restrict__ eh, const u16* __restrict__ Gy,
    const u16* __restrict__ WihS_bf, const u16* __restrict__ Whh_bf,
    const float* __restrict__ dbhh, const float* __restrict__ hinit,
    const u16* __restrict__ Wfc_bf, const float* __restrict__ fcB,
    u16* __restrict__ sxb, u16* __restrict__ hdd2,
    float* __restrict__ part, float* __restrict__ statsg,
    u16* __restrict__ XfcT, float* __restrict__ out,
    int* Pf, int* Xf, int* Hf, int* ticket)
{
  struct AS {
    u16   ehq[128][512];
    u16   oxb[512];
    float sc[128];
    float pt[8][512];
    float red[16];
  };
  struct WS { u16 stgl[32][520]; float gS[32][52]; float gH[32][52]; };
  struct FS { u16 Ab[128][520]; int tkS; };
  __shared__ __align__(16) char smem_[sizeof(AS)];
  int tid = threadIdx.x;
  int wave = tid>>6, lane = tid&63;

  if (blockIdx.x < NA_){
    // ===== role A: attention quarter (batch b, chunk q) =====
    AS& S = *(AS*)smem_;
    int b = blockIdx.x >> 2, q = blockIdx.x & 3;
    { // preload eh quarter, swizzled (once)
      const u16* ehg = eh + ((size_t)b*TX_ + q*128)*H_;
      int row = tid>>2, c0 = (tid&3)*128;
      #pragma unroll
      for (int j=0;j<16;++j){
        int u0 = c0 + j*8;
        uint4 v = *(const uint4*)(ehg + (size_t)row*H_ + u0);
        *(uint4*)&S.ehq[row][u0 ^ ((row&7)<<3)] = v;
      }
    }
    __syncthreads();
    bool bl = (lane&15) == 0;
    for (int t=0;t<TY_;++t){
      if (t > 0){
        if (tid < NW_) spin_rel(&Hf[tid], t);
        __syncthreads();
        asm volatile("" ::: "memory");
        if (tid < 64){
          u32x4 qv = ld16_c(hdd2 + (size_t)(t&1)*B_*H_ + (size_t)b*H_ + tid*8);
          *(u32x4*)&S.oxb[tid*8] = qv;
        }
      } else {
        S.oxb[tid] = f2bf(hinit[tid]);
      }
      __syncthreads();
      { // scores
        f32x4 acS = (f32x4){0.f,0.f,0.f,0.f};
        int arow = wave*16 + (lane&15);
        int swz = (arow&7)<<3;
        #pragma unroll
        for (int kt=0;kt<16;++kt){
          short8 bf = (short8){0,0,0,0,0,0,0,0};
          if (bl) bf = *(const short8*)&S.oxb[kt*32 + (lane>>4)*8];
          short8 af_ = *(const short8*)&S.ehq[arow][(kt*32 + (lane>>4)*8) ^ swz];
          acS = __builtin_amdgcn_mfma_f32_16x16x32_bf16(af_, bf, acS, 0,0,0);
        }
        if (bl){
          #pragma unroll
          for (int r=0;r<4;++r) S.sc[wave*16 + (lane>>4)*4 + r] = acS[r];
        }
      }
      __syncthreads();
      // local stats
      float mq, lq;
      {
        float v = (tid<128) ? S.sc[tid] : -3e38f;
        #pragma unroll
        for (int o=32;o>0;o>>=1) v = fmaxf(v, __shfl_xor(v, o));
        if (lane==0) S.red[wave] = v;
        __syncthreads();
        mq = fmaxf(S.red[0], S.red[1]);
        float e = 0.f;
        if (tid<128){ e = __expf(S.sc[tid] - mq); S.sc[tid] = e; }
        float s2 = e;
        #pragma unroll
        for (int o=32;o>0;o>>=1) s2 += __shfl_xor(s2, o);
        if (lane==0) S.red[8+wave] = s2;
        __syncthreads();
        lq = S.red[8] + S.red[9];
      }
      // PV partial (local-max-referenced, unnormalized)
      int u0 = lane*8, tseg = wave;
      f32x4 aLo = (f32x4){0.f,0.f,0.f,0.f}, aHi = (f32x4){0.f,0.f,0.f,0.f};
      #pragma unroll
      for (int j=0;j<16;++j){
        int tp = tseg*16 + j;
        short8 ev = *(const short8*)&S.ehq[tp][u0 ^ ((tp&7)<<3)];
        float av = S.sc[tp];
        aLo[0] = fmaf(bfu((u16)ev[0]), av, aLo[0]);
        aLo[1] = fmaf(bfu((u16)ev[1]), av, aLo[1]);
        aLo[2] = fmaf(bfu((u16)ev[2]), av, aLo[2]);
        aLo[3] = fmaf(bfu((u16)ev[3]), av, aLo[3]);
        aHi[0] = fmaf(bfu((u16)ev[4]), av, aHi[0]);
        aHi[1] = fmaf(bfu((u16)ev[5]), av, aHi[1]);
        aHi[2] = fmaf(bfu((u16)ev[6]), av, aHi[2]);
        aHi[3] = fmaf(bfu((u16)ev[7]), av, aHi[3]);
      }
      *(f32x4*)&S.pt[tseg][u0]   = aLo;
      *(f32x4*)&S.pt[tseg][u0+4] = aHi;
      __syncthreads();
      float sv = 0.f;
      #pragma unroll
      for (int gsg=0; gsg<8; ++gsg) sv += S.pt[gsg][tid];
      if (q != 0){
        st4f_c(&part[(size_t)(b*4+q)*512 + tid], sv);
        if (tid==0) st8_c(&statsg[(size_t)(b*4+q)*2], mq, lq);
        __syncthreads();
        if (tid==0) __hip_atomic_store(&Pf[b*4+q], t+1, __ATOMIC_RELAXED, __HIP_MEMORY_SCOPE_AGENT);
      } else {
        if (tid < 3) spin_rel(&Pf[b*4+1+tid], t+1);
        __syncthreads();
        asm volatile("" ::: "memory");
        // one burst: 3 partials + 3 stat pairs, single vmcnt
        float p1,p2,p3; f32x2 s1,s2,s3;
        {
          const float* pp1 = &part[(size_t)(b*4+1)*512 + tid];
          const float* pp2 = &part[(size_t)(b*4+2)*512 + tid];
          const float* pp3 = &part[(size_t)(b*4+3)*512 + tid];
          const float* ps1 = &statsg[(size_t)(b*4+1)*2];
          const float* ps2 = &statsg[(size_t)(b*4+2)*2];
          const float* ps3 = &statsg[(size_t)(b*4+3)*2];
          asm volatile(
            "global_load_dword %0, %6, off sc0 sc1\n\t"
            "global_load_dword %1, %7, off sc0 sc1\n\t"
            "global_load_dword %2, %8, off sc0 sc1\n\t"
            "global_load_dwordx2 %3, %9, off sc0 sc1\n\t"
            "global_load_dwordx2 %4, %10, off sc0 sc1\n\t"
            "global_load_dwordx2 %5, %11, off sc0 sc1\n\t"
            "s_waitcnt vmcnt(0)"
            : "=&v"(p1),"=&v"(p2),"=&v"(p3),"=&v"(s1),"=&v"(s2),"=&v"(s3)
            : "v"(pp1),"v"(pp2),"v"(pp3),"v"(ps1),"v"(ps2),"v"(ps3) : "memory");
        }
        float gmax = fmaxf(fmaxf(mq,s1.x), fmaxf(s2.x,s3.x));
        float e0=__expf(mq-gmax), e1=__expf(s1.x-gmax), e2=__expf(s2.x-gmax), e3=__expf(s3.x-gmax);
        float inv = 1.f/(lq*e0 + s1.y*e1 + s2.y*e2 + s3.y*e3);
        float sx = (sv*e0 + p1*e1 + p2*e2 + p3*e3) * inv;
        st_u16_c(&sxb[(size_t)b*H_ + tid], (unsigned)f2bf(sx));
        __syncthreads();
        if (tid==0) __hip_atomic_store(&Xf[b], t+1, __ATOMIC_RELAXED, __HIP_MEMORY_SCOPE_AGENT);
      }
    }
  } else if (blockIdx.x < NA_ + NW_){
    // ===== role W: gates for units [16g,16g+16), all 32 batches =====
    WS& S = *(WS*)smem_;
    int g = blockIdx.x - NA_;
    int pb = tid>>4, pu = tid&15, u = g*16 + pu;
    short8 fS[16], fH[16];
    int mt = wave/3, nt = wave%3;
    if (wave < 6){
      int row = nt*H_ + g*16 + (lane&15);
      int kb = (lane>>4)*8;
      #pragma unroll
      for (int ks=0;ks<16;++ks){
        fS[ks] = *(const short8*)(WihS_bf + (size_t)row*H_ + ks*32 + kb);
        fH[ks] = *(const short8*)(Whh_bf  + (size_t)row*H_ + ks*32 + kb);
      }
    }
    float bhR = dbhh[u], bhZ = dbhh[u+H_], bhN = dbhh[u+2*H_];
    float hloc = 0.f;

    for (int t=0;t<TY_;++t){
      size_t gyb = ((size_t)pb*TY_ + t)*G3_;
      float iR = bfu(Gy[gyb+u]), iZ = bfu(Gy[gyb+H_+u]), iN = bfu(Gy[gyb+2*H_+u]);
      // pre-Xf: gH from h(t-1)
      if (tid < NW_) spin_rel(&Hf[tid], t);
      __syncthreads();
      asm volatile("" ::: "memory");
      stage4_c(S.stgl, hdd2 + (size_t)(t&1)*B_*H_, tid);
      __syncthreads();
      int ar = mt*16 + (lane&15), ak = (lane>>4)*8;
      if (wave < 6){
        f32x4 acc = (f32x4){0.f,0.f,0.f,0.f};
        #pragma unroll
        for (int ks=0;ks<16;++ks)
          acc = __builtin_amdgcn_mfma_f32_16x16x32_bf16(*(const short8*)&S.stgl[ar][ks*32+ak], fH[ks], acc, 0,0,0);
        int dr = mt*16 + ((lane>>4)<<2), dc = nt*16 + (lane&15);
        #pragma unroll
        for (int r=0;r<4;++r) S.gH[dr+r][dc] = acc[r];
      }
      // wait sx, then gS
      if (tid < 32) spin_rel(&Xf[tid], t+1);
      __syncthreads();
      asm volatile("" ::: "memory");
      stage4_c(S.stgl, sxb, tid);
      __syncthreads();
      float sxv = bfu(S.stgl[pb][u]);
      if (wave < 6){
        f32x4 acc = (f32x4){0.f,0.f,0.f,0.f};
        #pragma unroll
        for (int ks=0;ks<16;++ks)
          acc = __builtin_amdgcn_mfma_f32_16x16x32_bf16(*(const short8*)&S.stgl[ar][ks*32+ak], fS[ks], acc, 0,0,0);
        int dr = mt*16 + ((lane>>4)<<2), dc = nt*16 + (lane&15);
        #pragma unroll
        for (int r=0;r<4;++r) S.gS[dr+r][dc] = acc[r];
      }
      __syncthreads();
      {
        float r = sigm(iR + S.gS[pb][pu]    + S.gH[pb][pu]    + bhR);
        float z = sigm(iZ + S.gS[pb][16+pu] + S.gH[pb][16+pu] + bhZ);
        float n = tanh_f(iN + S.gS[pb][32+pu] + r*(S.gH[pb][32+pu] + bhN));
        hloc = (1.f-z)*n + z*hloc;
        st_u16_c(&hdd2[(size_t)((t+1)&1)*B_*H_ + (size_t)pb*H_ + u], (unsigned)f2bf(hloc));
        st_u16_c(&XfcT[((size_t)t*B_ + pb)*H_ + u], (unsigned)f2bf(hloc + sxv));
      }
      __syncthreads();   // drain h + Xfc stores
      if (tid==0) __hip_atomic_store(&Hf[g], t+1, __ATOMIC_RELAXED, __HIP_MEMORY_SCOPE_AGENT);
    }
  } else {
    // ===== role FC: out = XfcT @ Wfc^T + fcB, ticket-fed by dec progress =====
    FS& S = *(FS*)smem_;
    int lr = lane & 15, lk = (lane>>4)*8;
    int m0 = (wave>>2)*64, n0w = (wave&3)*64;
    while (true){
      if (tid == 0)
        S.tkS = __hip_atomic_fetch_add(ticket, 1, __ATOMIC_RELAXED, __HIP_MEMORY_SCOPE_AGENT);
      __syncthreads();
      int tk = S.tkS;
      __syncthreads();
      if (tk >= 32*32) break;
      int tb = tk >> 5, c = tk & 31;
      int nbase = c*4;
      int nbend = (nbase+4 < 125) ? nbase+4 : 125;
      int te = 4*tb + 4; if (te > TY_) te = TY_;
      if (tid < NW_) spin_rel_slow(&Hf[tid], te);
      __syncthreads();
      asm volatile("" ::: "memory");
      { // A band: rows [tb*128, +128) of XfcT -> LDS (bypass). 16 iters = full 128x512.
        const u16* src = XfcT + (size_t)tb*128*H_;
        #pragma unroll
        for (int it2=0; it2<16; ++it2){
          int el = (it2*512 + tid)*8;
          int rr = el >> 9, cc = el & 511;
          u32x4 v = ld16_c(src + (size_t)rr*H_ + cc);
          *(u32x4*)&S.Ab[rr][cc] = v;
        }
      }
      __syncthreads();
      for (int nb = nbase; nb < nbend; ++nb){
        int ncol0 = nb*256 + n0w;
        f32x4 acc[4][4];
        #pragma unroll
        for (int i=0;i<4;++i)
          #pragma unroll
          for (int j=0;j<4;++j) acc[i][j] = (f32x4){0.f,0.f,0.f,0.f};
        for (int k0=0; k0<H_; k0+=32){
          short8 af[4], bfv[4];
          #pragma unroll
          for (int i=0;i<4;++i)
            af[i] = *(const short8*)&S.Ab[m0 + i*16 + lr][k0 + lk];
          #pragma unroll
          for (int j=0;j<4;++j)
            bfv[j] = *(const short8*)(Wfc_bf + (size_t)(ncol0 + j*16 + lr)*H_ + k0 + lk);
          #pragma unroll
          for (int i=0;i<4;++i)
            #pragma unroll
            for (int j=0;j<4;++j)
              acc[i][j] = __builtin_amdgcn_mfma_f32_16x16x32_bf16(af[i], bfv[j], acc[i][j], 0,0,0);
        }
        int rbase = (lane>>4)*4;
        #pragma unroll
        for (int i=0;i<4;++i)
          #pragma unroll
          for (int r=0;r<4;++r){
            int arow = m0 + i*16 + rbase + r;
            int t2 = tb*4 + (arow>>5), b2 = arow&31;
            if (t2 < TY_){
              #pragma unroll
              for (int j=0;j<4;++j){
                int col = ncol0 + j*16 + lr;
                out[((size_t)b2*TY_ + t2)*V_ + col] = acc[i][j][r] + fcB[col];
              }
            }
          }
        __syncthreads();
      }
    }
  }
}

extern "C" void kernel_launch(void* const* d_in, const int* in_sizes, int n_in,
                              void* d_out, int out_size, void* d_ws, size_t ws_size,
                              hipStream_t stream) {
  const int*   x     = (const int*)d_in[0];
  const int*   y     = (const int*)d_in[1];
  const float* emb   = (const float*)d_in[2];
  const float* eWih  = (const float*)d_in[3];
  const float* eWhh  = (const float*)d_in[4];
  const float* eBih  = (const float*)d_in[5];
  const float* eBhh  = (const float*)d_in[6];
  const float* dWih  = (const float*)d_in[7];
  const float* dWhh  = (const float*)d_in[8];
  const float* dBih  = (const float*)d_in[9];
  const float* dBhh  = (const float*)d_in[10];
  const float* hinit = (const float*)d_in[11];
  const float* fcW   = (const float*)d_in[12];
  const float* fcB   = (const float*)d_in[13];
  float* out = (float*)d_out;
  (void)in_sizes; (void)n_in; (void)out_size; (void)ws_size;

  char* p = (char*)d_ws;
  auto take = [&](size_t bytes)->char*{ char* r = p; p += (bytes + 255) & ~(size_t)255; return r; };
  u16* Wfc_bf   = (u16*)take((size_t)V_*H_*2);
  u16* ex_bf    = (u16*)take((size_t)B_*TX_*E_*2);
  u16* eWih_bf  = (u16*)take((size_t)G3_*E_*2);
  u16* Gx_bf    = (u16*)take((size_t)B_*TX_*G3_*2);
  u16* eh_bf    = (u16*)take((size_t)B_*TX_*H_*2);
  u16* embY_bf  = (u16*)take((size_t)4096*E_*2);
  u16* dWihE_bf = (u16*)take((size_t)G3_*E_*2);
  u16* Gy_bf    = (u16*)take((size_t)4096*G3_*2);
  u16* XfcT_bf  = (u16*)take((size_t)4096*H_*2);   // t-major [128][32][512]
  u16* eWhh_bf  = (u16*)take((size_t)G3_*H_*2);
  u16* dWhh_bf  = (u16*)take((size_t)G3_*H_*2);
  u16* dWihS_bf = (u16*)take((size_t)G3_*H_*2);
  u16* hgd      = (u16*)take((size_t)2*B_*H_*2);
  u16* hdd2     = (u16*)take((size_t)2*B_*H_*2);
  u16* sxb      = (u16*)take((size_t)B_*H_*2);
  float* part   = (float*)take((size_t)NA_*H_*4);
  float* statsg = (float*)take((size_t)NA_*2*4);
  int* flagsE   = (int*)take(256);
  int* ctrl     = (int*)take(4096);
  int* Pf = ctrl, *Xf = ctrl+128, *Hf = ctrl+160, *ticket = ctrl+200;

  hipMemsetAsync(flagsE, 0, 256, stream);
  hipMemsetAsync(ctrl, 0, 4096, stream);
  hipMemsetAsync(hgd, 0, (size_t)2*B_*H_*2, stream);
  hipMemsetAsync(hdd2, 0, (size_t)2*B_*H_*2, stream);

  cvt_rows<<<dim3(V_),  dim3(256), 0, stream>>>(fcW,  H_, 0, Wfc_bf,   H_);
  cvt_rows<<<dim3(G3_), dim3(256), 0, stream>>>(eWih, E_, 0, eWih_bf,  E_);
  cvt_rows<<<dim3(G3_), dim3(256), 0, stream>>>(dWih, E_+H_, 0, dWihE_bf, E_);
  cvt_rows<<<dim3(G3_), dim3(256), 0, stream>>>(eWhh, H_, 0, eWhh_bf,  H_);
  cvt_rows<<<dim3(G3_), dim3(256), 0, stream>>>(dWhh, H_, 0, dWhh_bf,  H_);
  cvt_rows<<<dim3(G3_), dim3(256), 0, stream>>>(dWih, E_+H_, E_, dWihS_bf, H_);

  gather_embed<<<dim3(B_*TX_), dim3(E_), 0, stream>>>(emb, x, ex_bf, TX_, TX_);
  gather_embed<<<dim3(B_*TY_), dim3(E_), 0, stream>>>(emb, y, embY_bf, TY_, 128);

  gemm_bf16<<<dim3(B_*TX_/128, G3_/128), dim3(256), 0, stream>>>(
      ex_bf, E_, eWih_bf, E_, Gx_bf, G3_, eBih, B_*TX_, E_, 1);
  gemm_bf16<<<dim3(32, G3_/128), dim3(256), 0, stream>>>(
      embY_bf, E_, dWihE_bf, E_, Gy_bf, G3_, dBih, B_*TY_, E_, 1);

  enc_v3<<<dim3(32), dim3(512), 0, stream>>>(Gx_bf, eWhh_bf, eBhh, eh_bf, hgd, flagsE);

  dec_v5<<<dim3(NA_+NW_+NF_), dim3(512), 0, stream>>>(
      eh_bf, Gy_bf, dWihS_bf, dWhh_bf, dBhh, hinit, Wfc_bf, fcB,
      sxb, hdd2, part, statsg, XfcT_bf, out, Pf, Xf, Hf, ticket);
}